// Round 7
// baseline (194.366 us; speedup 1.0000x reference)
//
#include <hip/hip_runtime.h>
#include <stdint.h>

// PersonalMed on MI355X. B=48,V=16,M=32,C=48,CM=8,D=128,OUT=256. f32 in/out.
// Round-7: TWO independent 16-row GRU groups per block, interleaved per step,
// so the two serial chains (ds_read -> MFMA -> gates -> barrier) overlap.
// Also: k_prep+k_front+k_embed_mon merged into one k_pre dispatch; visit-GRU
// streams 5,6 folded into the phase-0 GRU dispatch. 4 dispatches total.

typedef unsigned short u16;
typedef uint32_t u32;
typedef short bf8 __attribute__((ext_vector_type(8)));   // 8 bf16 = 4 VGPRs
typedef float f4 __attribute__((ext_vector_type(4)));

static __device__ __forceinline__ float bf2f(u16 b){ u32 u=((u32)b)<<16; float f; __builtin_memcpy(&f,&u,4); return f; }
static __device__ __forceinline__ u16 f2bf(float f){ u32 u; __builtin_memcpy(&u,&f,4); u32 r=(u+0x7fffu+((u>>16)&1u))>>16; return (u16)r; }
static __device__ __forceinline__ f4 mfma16(bf8 a, bf8 b, f4 c){ return __builtin_amdgcn_mfma_f32_16x16x32_bf16(a,b,c,0,0,0); }

#if __has_builtin(__builtin_amdgcn_exp2f)
static __device__ __forceinline__ float fexp2(float x){ return __builtin_amdgcn_exp2f(x); }
#else
static __device__ __forceinline__ float fexp2(float x){ float r; asm volatile("v_exp_f32 %0, %1" : "=v"(r) : "v"(x)); return r; }
#endif
#if __has_builtin(__builtin_amdgcn_rcpf)
static __device__ __forceinline__ float frcp(float x){ return __builtin_amdgcn_rcpf(x); }
#else
static __device__ __forceinline__ float frcp(float x){ float r; asm volatile("v_rcp_f32 %0, %1" : "=v"(r) : "v"(x)); return r; }
#endif
#define LOG2E 1.44269504089f
static __device__ __forceinline__ float sigm(float x){ return frcp(1.0f + fexp2(-LOG2E*x)); }
static __device__ __forceinline__ float tanh_f(float x){ return 1.0f - 2.0f*frcp(1.0f + fexp2((2.0f*LOG2E)*x)); }

// ================= k_pre: weights conv + visit bags + weight/age + mon bag =================
// grid (3072,4), block 256.
//  y=0/1: monitor embedding bag p=y (f32 tables, 8 rows/block)
//  y=2  : GRU weights f32->bf16 (x<1152)
//  y=3  : visit bags (x<1152, 2 rows/block) + weight/age linears (1152<=x<1920)
__global__ __launch_bounds__(256) void k_pre(const int* __restrict__ vids, const int* __restrict__ mids,
    const float* __restrict__ embv, const float* __restrict__ embm,
    const float* __restrict__ wv, const float* __restrict__ av,
    const float* __restrict__ ww, const float* __restrict__ wb,
    const float* __restrict__ aw, const float* __restrict__ ab,
    const float* __restrict__ mWih_f, const float* __restrict__ mWhh_f,
    const float* __restrict__ vWih_f, const float* __restrict__ vWhh_f,
    u16* __restrict__ mWih_b, u16* __restrict__ mWhh_b,
    u16* __restrict__ vWih_b, u16* __restrict__ vWhh_b,
    u16* __restrict__ mon_xT, u16* __restrict__ vis_org, u16* __restrict__ hin2T){
  int y = blockIdx.y;
  if (y < 2){
    int p = y;
    int rid = threadIdx.x >> 5, lane32 = threadIdx.x & 31, d0 = lane32*4;
    __shared__ int ids[8][16];
    if (threadIdx.x < 128){
      int rr = threadIdx.x >> 4, c = threadIdx.x & 15;
      int f = 2*p + (c>>3), cm = c & 7;
      ids[rr][c] = mids[((size_t)f*24576 + (size_t)blockIdx.x*8 + rr)*8 + cm];
    }
    __syncthreads();
    const float* e1 = embm + (size_t)(2*p)*1000*128;
    const float* e2 = embm + (size_t)(2*p+1)*1000*128;
    float a0=0.f,a1=0.f,a2=0.f,a3=0.f;
    #pragma unroll
    for (int c = 0; c < 8; ++c){
      int i1 = ids[rid][c], i2 = ids[rid][8+c];
      if (i1 && i2){
        float4 a = *(const float4*)(e1 + (size_t)i1*128 + d0);
        float4 b = *(const float4*)(e2 + (size_t)i2*128 + d0);
        a0 += a.x*b.x; a1 += a.y*b.y; a2 += a.z*b.z; a3 += a.w*b.w;
      }
    }
    size_t nm = (size_t)blockIdx.x*8 + rid;
    int bv = (int)(nm >> 5), m = (int)(nm & 31);
    ushort4 o = { f2bf(a0), f2bf(a1), f2bf(a2), f2bf(a3) };
    *(ushort4*)(mon_xT + (size_t)p*24576*128 + ((size_t)m*768 + bv)*128 + d0) = o;
  } else if (y == 2){
    int i = blockIdx.x*256 + threadIdx.x;          // float4 index, total 294912
    if (i >= 294912) return;
    const float* s; u16* d; int off;
    if (i < 61440)      { s = mWih_f; d = mWih_b; off = i; }
    else if (i < 122880){ s = mWhh_f; d = mWhh_b; off = i - 61440; }
    else if (i < 208896){ s = vWih_f; d = vWih_b; off = i - 122880; }
    else                { s = vWhh_f; d = vWhh_b; off = i - 208896; }
    float4 v = *(const float4*)(s + (size_t)off*4);
    ushort4 o = { f2bf(v.x), f2bf(v.y), f2bf(v.z), f2bf(v.w) };
    *(ushort4*)(d + (size_t)off*4) = o;
  } else {
    int x = blockIdx.x;
    int sub = threadIdx.x >> 7, d = threadIdx.x & 127;
    if (x < 1152){                                  // visit bags: rows 2x,2x+1 of 2304
      __shared__ int ids[2][48];
      int row = x*2 + sub;
      int k = row / 768, bv = row - k*768;
      if (d < 48) ids[sub][d] = vids[((size_t)k*768 + bv)*48 + d];
      __syncthreads();
      const float* eb = embv + (size_t)k*2000*128;
      float acc = 0.f;
      #pragma unroll 4
      for (int c = 0; c < 48; ++c){ int id = ids[sub][c]; if (id) acc += eb[(size_t)id*128 + d]; }
      vis_org[((size_t)k*768 + bv)*128 + d] = f2bf(acc);
    } else if (x < 1920){                           // weight/age: rows of 1536
      int grow = (x - 1152)*2 + sub;
      int sidx = grow >= 768 ? 1 : 0;
      int row = grow - sidx*768;
      const float* vals = sidx ? av : wv;
      const float* wgt  = sidx ? aw : ww;
      const float* bias = sidx ? ab : wb;
      float v = vals[row];
      float h = (v != 0.f) ? (v * wgt[d] + bias[d]) : 0.f;
      int b = row >> 4, vv = row & 15;
      hin2T[((size_t)(5+sidx)*768 + (size_t)vv*48 + b)*128 + d] = f2bf(h);
    }
  }
}

// ================= fused GRU, 2 groups/block =================
// phase 0: grid (24,7).
//   y<5 : monitor-level stream y, T=32, groups (2x,2x+1) of 48.
//         y<2: A=mon_xT[y], rstride=768*128 ; y>=2: A=vis_org[y-2], rstride=0.
//         weights mgru[y]; out hin2T[slot], slot=0x32140 nibble, row=(lq*4+r)*48+g.
//   y=5,6: visit-level stream y (x<2), T=16, A=hin2T[y], rstride=48*128,
//         weights vgru[y]; out h2[y], row=g*16+lq*4+r. x=1 handles group 2 twice (benign).
// phase 1: grid (2,5). visit-level streams s=0..4, vi=0x6514320 nibble.

#define BARRIER() asm volatile("s_waitcnt lgkmcnt(0)\n\ts_barrier" ::: "memory")

#define ALOADg(S, ap, tt) { int t_=(tt); if (t_>=T) t_=0; \
  const u16* p_ = ap + (size_t)t_*rstride; \
  S[0]=*(const bf8*)(p_); S[1]=*(const bf8*)(p_+32); \
  S[2]=*(const bf8*)(p_+64); S[3]=*(const bf8*)(p_+96); }

#define GIMMg(G0,G1,G2,S) { \
  f4 t0_={biv[0],biv[0],biv[0],biv[0]}; G0=t0_; \
  f4 t1_={biv[1],biv[1],biv[1],biv[1]}; G1=t1_; \
  f4 t2_={biv[2],biv[2],biv[2],biv[2]}; G2=t2_; \
  G0=mfma16(S[0],wfi[0][0],G0); G0=mfma16(S[1],wfi[0][1],G0); \
  G0=mfma16(S[2],wfi[0][2],G0); G0=mfma16(S[3],wfi[0][3],G0); \
  G1=mfma16(S[0],wfi[1][0],G1); G1=mfma16(S[1],wfi[1][1],G1); \
  G1=mfma16(S[2],wfi[1][2],G1); G1=mfma16(S[3],wfi[1][3],G1); \
  G2=mfma16(S[0],wfi[2][0],G2); G2=mfma16(S[1],wfi[2][1],G2); \
  G2=mfma16(S[2],wfi[2][2],G2); G2=mfma16(S[3],wfi[2][3],G2); }

#define GHRDg(a0,a1,a2,grp) { \
  bf8 hf0_=*(const bf8*)&hlds[cur][grp][lr][lq*8]; \
  bf8 hf1_=*(const bf8*)&hlds[cur][grp][lr][32+lq*8]; \
  bf8 hf2_=*(const bf8*)&hlds[cur][grp][lr][64+lq*8]; \
  bf8 hf3_=*(const bf8*)&hlds[cur][grp][lr][96+lq*8]; \
  f4 i0_={bhv[0],bhv[0],bhv[0],bhv[0]}; a0=i0_; \
  f4 i1_={bhv[1],bhv[1],bhv[1],bhv[1]}; a1=i1_; \
  f4 i2_={bhv[2],bhv[2],bhv[2],bhv[2]}; a2=i2_; \
  a0=mfma16(hf0_,wfh[0][0],a0); a0=mfma16(hf1_,wfh[0][1],a0); \
  a0=mfma16(hf2_,wfh[0][2],a0); a0=mfma16(hf3_,wfh[0][3],a0); \
  a1=mfma16(hf0_,wfh[1][0],a1); a1=mfma16(hf1_,wfh[1][1],a1); \
  a1=mfma16(hf2_,wfh[1][2],a1); a1=mfma16(hf3_,wfh[1][3],a1); \
  a2=mfma16(hf0_,wfh[2][0],a2); a2=mfma16(hf1_,wfh[2][1],a2); \
  a2=mfma16(hf2_,wfh[2][2],a2); a2=mfma16(hf3_,wfh[2][3],a2); }

#define GATESg(G0,G1,G2,a0,a1,a2,hp,grp,nxt) { \
  _Pragma("unroll") \
  for (int r=0;r<4;++r){ \
    float rr_=sigm(G0[r]+a0[r]); \
    float zz_=sigm(G1[r]+a1[r]); \
    float nn_=tanh_f(G2[r]+rr_*a2[r]); \
    float hv_=(1.0f-zz_)*nn_+zz_*hp[r]; hp[r]=hv_; \
    hlds[nxt][grp][lq*4+r][w*16+lr]=f2bf(hv_); } }

#define STEP0P() { int nxt_=cur^1; \
  f4 aA0={bhv[0],bhv[0],bhv[0],bhv[0]}, aA1={bhv[1],bhv[1],bhv[1],bhv[1]}, aA2={bhv[2],bhv[2],bhv[2],bhv[2]}; \
  f4 aB0=aA0, aB1=aA1, aB2=aA2; \
  GATESg(eA0,eA1,eA2,aA0,aA1,aA2,hpA,0,nxt_); \
  GATESg(eB0,eB1,eB2,aB0,aB1,aB2,hpB,1,nxt_); \
  BARRIER(); cur=nxt_; }

#define STEPP(GA0,GA1,GA2,GB0,GB1,GB2,tt) { int nxt_=cur^1; \
  f4 aA0,aA1,aA2,aB0,aB1,aB2; \
  GHRDg(aA0,aA1,aA2,0); \
  GHRDg(aB0,aB1,aB2,1); \
  GATESg(GA0,GA1,GA2,aA0,aA1,aA2,hpA,0,nxt_); \
  GATESg(GB0,GB1,GB2,aB0,aB1,aB2,hpB,1,nxt_); \
  BARRIER(); cur=nxt_; \
  if ((tt)+2 < T){ GIMMg(GA0,GA1,GA2,SA); GIMMg(GB0,GB1,GB2,SB); } \
  ALOADg(SA,apA,(tt)+3); ALOADg(SB,apB,(tt)+3); }

#define STEPC() { int nxt_=cur^1; \
  f4 aA0,aA1,aA2,aB0,aB1,aB2; \
  GHRDg(aA0,aA1,aA2,0); \
  GHRDg(aB0,aB1,aB2,1); \
  GATESg(eA0,eA1,eA2,aA0,aA1,aA2,hpA,0,nxt_); \
  GATESg(eB0,eB1,eB2,aB0,aB1,aB2,hpB,1,nxt_); \
  BARRIER(); cur=nxt_; }

__global__ __launch_bounds__(512, 2) void k_gru(int phase,
    const u16* __restrict__ mon_xT, const u16* __restrict__ vis_org,
    u16* __restrict__ hin2T, u16* __restrict__ h2,
    const u16* __restrict__ mWih, const float* __restrict__ mbih,
    const u16* __restrict__ mWhh, const float* __restrict__ mbhh,
    const u16* __restrict__ vWih, const float* __restrict__ vbih,
    const u16* __restrict__ vWhh, const float* __restrict__ vbhh){
  int s = blockIdx.y;
  const u16* A; size_t rstride; int T, oMode, gA, gB;
  const u16 *Wi, *Wh; const float *bi2, *bh2; u16* ho;
  bool vjob = (phase == 1) || (s >= 5);
  if (!vjob){
    T = 32; oMode = 0; gA = 2*blockIdx.x; gB = gA + 1;
    if (s < 2){ A = mon_xT + (size_t)s*24576*128; rstride = 768*128; }
    else      { A = vis_org + (size_t)(s-2)*768*128; rstride = 0; }
    Wi = mWih + (size_t)s*49152; Wh = mWhh + (size_t)s*49152;
    bi2 = mbih + (size_t)s*384;  bh2 = mbhh + (size_t)s*384;
    int slot = (0x32140u >> (4*s)) & 15;
    ho = hin2T + (size_t)slot*768*128;
  } else {
    if (blockIdx.x >= 2) return;
    T = 16; oMode = 1; gA = 2*blockIdx.x; gB = gA + 1; if (gB > 2) gB = 2;
    A = hin2T + (size_t)s*768*128; rstride = 48*128;
    int vi = (0x6514320u >> (4*s)) & 15;
    Wi = vWih + (size_t)vi*49152; Wh = vWhh + (size_t)vi*49152;
    bi2 = vbih + (size_t)vi*384;  bh2 = vbhh + (size_t)vi*384;
    ho = h2 + (size_t)s*48*128;
  }

  int w = threadIdx.x >> 6, l = threadIdx.x & 63;
  int lr = l & 15, lq = l >> 4;

  // wave w owns gate-col-chunk w*16..+16 of r,z,n (tiles w, 8+w, 16+w)
  bf8 wfi[3][4], wfh[3][4]; float biv[3], bhv[3];
  #pragma unroll
  for (int j = 0; j < 3; ++j){
    int colb = (w + 8*j)*16;
    const u16* wpi = Wi + (size_t)(colb + lr)*128 + lq*8;
    const u16* wph = Wh + (size_t)(colb + lr)*128 + lq*8;
    #pragma unroll
    for (int kt = 0; kt < 4; ++kt){
      wfi[j][kt] = *(const bf8*)(wpi + kt*32);
      wfh[j][kt] = *(const bf8*)(wph + kt*32);
    }
    biv[j] = bi2[colb + lr];
    bhv[j] = bh2[colb + lr];
  }

  const u16* apA = A + (size_t)(gA*16 + lr)*128 + lq*8;
  const u16* apB = A + (size_t)(gB*16 + lr)*128 + lq*8;
  __shared__ u16 hlds[2][2][16][132];
  float hpA[4] = {0.f,0.f,0.f,0.f}, hpB[4] = {0.f,0.f,0.f,0.f};
  int cur = 0;

  if (rstride){
    bf8 SA[4], SB[4];
    f4 eA0,eA1,eA2, oA0,oA1,oA2, eB0,eB1,eB2, oB0,oB1,oB2;
    ALOADg(SA,apA,0); ALOADg(SB,apB,0);
    GIMMg(eA0,eA1,eA2,SA); GIMMg(eB0,eB1,eB2,SB);      // gi(0)
    ALOADg(SA,apA,1); ALOADg(SB,apB,1);
    GIMMg(oA0,oA1,oA2,SA); GIMMg(oB0,oB1,oB2,SB);      // gi(1)
    ALOADg(SA,apA,2); ALOADg(SB,apB,2);
    STEP0P();                                          // t=0 (gh=bhh)
    GIMMg(eA0,eA1,eA2,SA); GIMMg(eB0,eB1,eB2,SB);      // gi(2)
    ALOADg(SA,apA,3); ALOADg(SB,apB,3);
    STEPP(oA0,oA1,oA2,oB0,oB1,oB2,1);                  // t=1, builds gi(3), loads A(4)
    for (int t = 2; t < T; t += 2){
      STEPP(eA0,eA1,eA2,eB0,eB1,eB2,t);
      STEPP(oA0,oA1,oA2,oB0,oB1,oB2,t+1);
    }
  } else {
    bf8 SA[4], SB[4];
    f4 eA0,eA1,eA2, eB0,eB1,eB2;
    ALOADg(SA,apA,0); ALOADg(SB,apB,0);
    GIMMg(eA0,eA1,eA2,SA); GIMMg(eB0,eB1,eB2,SB);      // constant gi
    STEP0P();
    for (int t = 1; t < T; ++t) STEPC();
  }

  if (oMode == 0){
    #pragma unroll
    for (int r = 0; r < 4; ++r){
      ho[((size_t)(lq*4+r)*48 + gA)*128 + w*16 + lr] = f2bf(hpA[r]);
      ho[((size_t)(lq*4+r)*48 + gB)*128 + w*16 + lr] = f2bf(hpB[r]);
    }
  } else {
    #pragma unroll
    for (int r = 0; r < 4; ++r){
      ho[((size_t)(gA*16 + lq*4 + r))*128 + w*16 + lr] = f2bf(hpA[r]);
      ho[((size_t)(gB*16 + lq*4 + r))*128 + w*16 + lr] = f2bf(hpB[r]);
    }
  }
}

// ================= final projection =================
__global__ __launch_bounds__(256) void k_final(const u16* __restrict__ h2,
                                               const float* __restrict__ W,
                                               const float* __restrict__ Bias,
                                               float* __restrict__ out){
  int b = blockIdx.x, t = threadIdx.x;
  __shared__ float emb[896];
  for (int i = t; i < 896; i += 256){
    int j = i >> 7, d = i & 127;
    float v = bf2f(h2[((size_t)j*48 + b)*128 + d]);
    if (j >= 1 && j <= 3) v *= 2.0f;   // slots 1..3 appear twice in reference sum
    emb[i] = fmaxf(v, 0.f);
  }
  __syncthreads();
  float acc = Bias[t];
  const float* wp = W + (size_t)t*896;
  for (int i = 0; i < 896; i += 8){
    float4 w0 = *(const float4*)(wp + i);
    float4 w1 = *(const float4*)(wp + i + 4);
    acc += w0.x*emb[i]   + w0.y*emb[i+1] + w0.z*emb[i+2] + w0.w*emb[i+3];
    acc += w1.x*emb[i+4] + w1.y*emb[i+5] + w1.z*emb[i+6] + w1.w*emb[i+7];
  }
  out[(size_t)b*256 + t] = acc;
}

extern "C" void kernel_launch(void* const* d_in, const int* in_sizes, int n_in,
                              void* d_out, int out_size, void* d_ws, size_t ws_size,
                              hipStream_t stream){
  const int*   visit_ids   = (const int*)d_in[0];
  const int*   mon_ids     = (const int*)d_in[1];
  const float* weight_vals = (const float*)d_in[2];
  const float* age_vals    = (const float*)d_in[3];
  const float* emb_visit   = (const float*)d_in[4];
  const float* emb_mon     = (const float*)d_in[5];
  const float* mgru_Wih    = (const float*)d_in[6];
  const float* mgru_Whh    = (const float*)d_in[7];
  const float* mgru_bih    = (const float*)d_in[8];
  const float* mgru_bhh    = (const float*)d_in[9];
  const float* vgru_Wih    = (const float*)d_in[10];
  const float* vgru_Whh    = (const float*)d_in[11];
  const float* vgru_bih    = (const float*)d_in[12];
  const float* vgru_bhh    = (const float*)d_in[13];
  const float* fc_w_w      = (const float*)d_in[14];
  const float* fc_w_b      = (const float*)d_in[15];
  const float* fc_a_w      = (const float*)d_in[16];
  const float* fc_a_b      = (const float*)d_in[17];
  const float* fc_out_w    = (const float*)d_in[18];
  const float* fc_out_b    = (const float*)d_in[19];

  char* ws = (char*)d_ws;
  size_t o = 0;
  u16* mWih_b  = (u16*)(ws+o); o += 5ull*384*128*2;
  u16* mWhh_b  = (u16*)(ws+o); o += 5ull*384*128*2;
  u16* vWih_b  = (u16*)(ws+o); o += 7ull*384*128*2;
  u16* vWhh_b  = (u16*)(ws+o); o += 7ull*384*128*2;
  u16* mon_xT  = (u16*)(ws+o); o += 2ull*24576*128*2;    // [p][m*768+bv][128]
  u16* vis_org = (u16*)(ws+o); o += 3ull*768*128*2;
  u16* hin2T   = (u16*)(ws+o); o += 7ull*768*128*2;      // [slot][v*48+b][128]
  u16* h2      = (u16*)(ws+o); o += 7ull*48*128*2;       // ~16.6 MB total

  k_pre<<<dim3(3072,4), 256, 0, stream>>>(visit_ids, mon_ids, emb_visit, emb_mon,
      weight_vals, age_vals, fc_w_w, fc_w_b, fc_a_w, fc_a_b,
      mgru_Wih, mgru_Whh, vgru_Wih, vgru_Whh,
      mWih_b, mWhh_b, vWih_b, vWhh_b,
      mon_xT, vis_org, hin2T);
  // phase 0: monitor-level streams 0..4 + visit-level streams 5,6
  k_gru<<<dim3(24,7), 512, 0, stream>>>(0, mon_xT, vis_org, hin2T, h2,
      mWih_b, mgru_bih, mWhh_b, mgru_bhh, vWih_b, vgru_bih, vWhh_b, vgru_bhh);
  // phase 1: visit-level streams 0..4
  k_gru<<<dim3(2,5), 512, 0, stream>>>(1, mon_xT, vis_org, hin2T, h2,
      mWih_b, mgru_bih, mWhh_b, mgru_bhh, vWih_b, vgru_bih, vWhh_b, vgru_bhh);
  k_final<<<48, 256, 0, stream>>>(h2, fc_out_w, fc_out_b, (float*)d_out);
}

// Round 8
// 170.929 us; speedup vs baseline: 1.1371x; 1.1371x over previous
//
#include <hip/hip_runtime.h>
#include <stdint.h>

// PersonalMed on MI355X. B=48,V=16,M=32,C=48,CM=8,D=128,OUT=256. f32 in/out.
// Round-8: 2 independent GRU chains per 512-thr block, register-dieted:
//  - gh chained into gi accumulator via MFMA C-operand (r/z gates merged;
//    n-gate keeps separate AN since n = tanh(gi_n + r*gh_n)).
//  - single-buffer S prefetch (1 interval ahead), shared wfi/wfh (same stream).
//  - broadcast streams: const-gi path, wfi transient in prologue.
//  Est. ~230 live VGPRs < 256 cap of __launch_bounds__(512,2).

typedef unsigned short u16;
typedef uint32_t u32;
typedef short bf8 __attribute__((ext_vector_type(8)));   // 8 bf16 = 4 VGPRs
typedef float f4 __attribute__((ext_vector_type(4)));

static __device__ __forceinline__ float bf2f(u16 b){ u32 u=((u32)b)<<16; float f; __builtin_memcpy(&f,&u,4); return f; }
static __device__ __forceinline__ u16 f2bf(float f){ u32 u; __builtin_memcpy(&u,&f,4); u32 r=(u+0x7fffu+((u>>16)&1u))>>16; return (u16)r; }
static __device__ __forceinline__ float bflo(u32 u){ u32 x=u<<16; float f; __builtin_memcpy(&f,&x,4); return f; }
static __device__ __forceinline__ float bfhi(u32 u){ u32 x=u&0xffff0000u; float f; __builtin_memcpy(&f,&x,4); return f; }
static __device__ __forceinline__ f4 mfma16(bf8 a, bf8 b, f4 c){ return __builtin_amdgcn_mfma_f32_16x16x32_bf16(a,b,c,0,0,0); }

#if __has_builtin(__builtin_amdgcn_exp2f)
static __device__ __forceinline__ float fexp2(float x){ return __builtin_amdgcn_exp2f(x); }
#else
static __device__ __forceinline__ float fexp2(float x){ float r; asm volatile("v_exp_f32 %0, %1" : "=v"(r) : "v"(x)); return r; }
#endif
#if __has_builtin(__builtin_amdgcn_rcpf)
static __device__ __forceinline__ float frcp(float x){ return __builtin_amdgcn_rcpf(x); }
#else
static __device__ __forceinline__ float frcp(float x){ float r; asm volatile("v_rcp_f32 %0, %1" : "=v"(r) : "v"(x)); return r; }
#endif
#define LOG2E 1.44269504089f
static __device__ __forceinline__ float sigm(float x){ return frcp(1.0f + fexp2(-LOG2E*x)); }
static __device__ __forceinline__ float tanh_f(float x){ return 1.0f - 2.0f*frcp(1.0f + fexp2((2.0f*LOG2E)*x)); }

// ================= k_prep: f32->bf16 (GRU weights + emb_mon + emb_visit) =================
// flat float4 ranges: mWih 61440 | mWhh 61440 | vWih 86016 | vWhh 86016 | embm 128000 | embv 192000
__global__ __launch_bounds__(256) void k_prep(
    const float* __restrict__ s0, const float* __restrict__ s1,
    const float* __restrict__ s2, const float* __restrict__ s3,
    const float* __restrict__ s4, const float* __restrict__ s5,
    u16* __restrict__ d0, u16* __restrict__ d1, u16* __restrict__ d2,
    u16* __restrict__ d3, u16* __restrict__ d4, u16* __restrict__ d5){
  int i = blockIdx.x*256 + threadIdx.x;
  const float* s; u16* d; int off;
  if      (i < 61440)  { s=s0; d=d0; off=i; }
  else if (i < 122880) { s=s1; d=d1; off=i-61440; }
  else if (i < 208896) { s=s2; d=d2; off=i-122880; }
  else if (i < 294912) { s=s3; d=d3; off=i-208896; }
  else if (i < 422912) { s=s4; d=d4; off=i-294912; }
  else if (i < 614912) { s=s5; d=d5; off=i-422912; }
  else return;
  float4 v = *(const float4*)(s + (size_t)off*4);
  ushort4 o = { f2bf(v.x), f2bf(v.y), f2bf(v.z), f2bf(v.w) };
  *(ushort4*)(d + (size_t)off*4) = o;
}

// ================= k_bags: mon bag (bf16) + visit bags (bf16) + weight/age =================
// grid (3072,3) block 256. y=0/1: mon p=y, 8 rows/block. y=2: x<1152 visit bags
// (2 rows/block of 2304), 1152<=x<1920 weight/age (2 rows/block of 1536).
__global__ __launch_bounds__(256) void k_bags(const int* __restrict__ vids, const int* __restrict__ mids,
    const u16* __restrict__ embv_b, const u16* __restrict__ embm_b,
    const float* __restrict__ wv, const float* __restrict__ av,
    const float* __restrict__ ww, const float* __restrict__ wb,
    const float* __restrict__ aw, const float* __restrict__ ab,
    u16* __restrict__ mon_xT, u16* __restrict__ vis_org, u16* __restrict__ hin2T){
  int y = blockIdx.y;
  if (y < 2){
    int p = y;
    int rid = threadIdx.x >> 5, lane32 = threadIdx.x & 31, d0 = lane32*4;
    __shared__ int ids[8][16];
    if (threadIdx.x < 128){
      int rr = threadIdx.x >> 4, c = threadIdx.x & 15;
      int f = 2*p + (c>>3), cm = c & 7;
      ids[rr][c] = mids[((size_t)f*24576 + (size_t)blockIdx.x*8 + rr)*8 + cm];
    }
    __syncthreads();
    const u16* e1 = embm_b + (size_t)(2*p)*1000*128;
    const u16* e2 = embm_b + (size_t)(2*p+1)*1000*128;
    float a0=0.f,a1=0.f,a2=0.f,a3=0.f;
    #pragma unroll
    for (int c = 0; c < 8; ++c){
      int i1 = ids[rid][c], i2 = ids[rid][8+c];
      if (i1 && i2){
        uint2 a = *(const uint2*)(e1 + (size_t)i1*128 + d0);
        uint2 b = *(const uint2*)(e2 + (size_t)i2*128 + d0);
        a0 += bflo(a.x)*bflo(b.x); a1 += bfhi(a.x)*bfhi(b.x);
        a2 += bflo(a.y)*bflo(b.y); a3 += bfhi(a.y)*bfhi(b.y);
      }
    }
    size_t nm = (size_t)blockIdx.x*8 + rid;
    int bv = (int)(nm >> 5), m = (int)(nm & 31);
    ushort4 o = { f2bf(a0), f2bf(a1), f2bf(a2), f2bf(a3) };
    *(ushort4*)(mon_xT + (size_t)p*24576*128 + ((size_t)m*768 + bv)*128 + d0) = o;
  } else {
    int x = blockIdx.x;
    int sub = threadIdx.x >> 7, d = threadIdx.x & 127;
    if (x < 1152){
      __shared__ int ids[2][48];
      int row = x*2 + sub;
      int k = row / 768, bv = row - k*768;
      if (d < 48) ids[sub][d] = vids[((size_t)k*768 + bv)*48 + d];
      __syncthreads();
      const u16* eb = embv_b + (size_t)k*2000*128;
      float acc = 0.f;
      #pragma unroll 4
      for (int c = 0; c < 48; ++c){ int id = ids[sub][c]; if (id) acc += bf2f(eb[(size_t)id*128 + d]); }
      vis_org[((size_t)k*768 + bv)*128 + d] = f2bf(acc);
    } else if (x < 1920){
      int grow = (x - 1152)*2 + sub;
      int sidx = grow >= 768 ? 1 : 0;
      int row = grow - sidx*768;
      const float* vals = sidx ? av : wv;
      const float* wgt  = sidx ? aw : ww;
      const float* bias = sidx ? ab : wb;
      float v = vals[row];
      float h = (v != 0.f) ? (v * wgt[d] + bias[d]) : 0.f;
      int b = row >> 4, vv = row & 15;
      hin2T[((size_t)(5+sidx)*768 + (size_t)vv*48 + b)*128 + d] = f2bf(h);
    }
  }
}

// ================= fused GRU: 2 chains/block, reg-dieted =================
// phase 0: grid (24,7). s<5: monitor level, T=32, chains {2x,2x+1} of 48.
//   s<2: A=mon_xT[s], rstride=768*128 ; s in 2..4: A=vis_org[s-2], rstride=0.
//   out hin2T[slot], slot=0x32140 nibble, row=(lq*4+r)*48+g.
//   s=5,6 (x<2): visit level on hin2T[s], T=16, vgru[s], out h2[s].
// phase 1: grid (2,5). visit level s=0..4, vi=0x6514320 nibble, out h2[s].
// chains: bx=0 -> {0,1}; bx=1 -> {2,2} (duplicate benign).

#define BARRIER() asm volatile("s_waitcnt lgkmcnt(0)\n\ts_barrier" ::: "memory")

#define ALOAD(S, ap, tt) { int t_=(tt); if(t_>=T) t_=0; \
  const u16* p_ = ap + (size_t)t_*rstride; \
  S[0]=*(const bf8*)(p_); S[1]=*(const bf8*)(p_+32); \
  S[2]=*(const bf8*)(p_+64); S[3]=*(const bf8*)(p_+96); }

// G = {birz+bhrz, .., bin} + S@wfi   (G[2] = n-gate input part only)
#define GIMM(G, S) { \
  f4 i0_={bs0_,bs0_,bs0_,bs0_}; G[0]=i0_; \
  f4 i1_={bs1_,bs1_,bs1_,bs1_}; G[1]=i1_; \
  f4 i2_={bin_,bin_,bin_,bin_}; G[2]=i2_; \
  _Pragma("unroll") for(int k_=0;k_<4;++k_) G[0]=mfma16(S[k_],wfi[0][k_],G[0]); \
  _Pragma("unroll") for(int k_=0;k_<4;++k_) G[1]=mfma16(S[k_],wfi[1][k_],G[1]); \
  _Pragma("unroll") for(int k_=0;k_<4;++k_) G[2]=mfma16(S[k_],wfi[2][k_],G[2]); }

// gh: accumulate h@Whh into G[0],G[1] (C-operand chaining); AN = bhn + h@Whh_n
#define GH(G, AN, grp) { \
  bf8 hf0_=*(const bf8*)&hlds[cur][grp][lr][lq*8]; \
  bf8 hf1_=*(const bf8*)&hlds[cur][grp][lr][32+lq*8]; \
  bf8 hf2_=*(const bf8*)&hlds[cur][grp][lr][64+lq*8]; \
  bf8 hf3_=*(const bf8*)&hlds[cur][grp][lr][96+lq*8]; \
  f4 an_={bhn_,bhn_,bhn_,bhn_}; AN=an_; \
  G[0]=mfma16(hf0_,wfh[0][0],G[0]); G[0]=mfma16(hf1_,wfh[0][1],G[0]); \
  G[0]=mfma16(hf2_,wfh[0][2],G[0]); G[0]=mfma16(hf3_,wfh[0][3],G[0]); \
  G[1]=mfma16(hf0_,wfh[1][0],G[1]); G[1]=mfma16(hf1_,wfh[1][1],G[1]); \
  G[1]=mfma16(hf2_,wfh[1][2],G[1]); G[1]=mfma16(hf3_,wfh[1][3],G[1]); \
  AN=mfma16(hf0_,wfh[2][0],AN); AN=mfma16(hf1_,wfh[2][1],AN); \
  AN=mfma16(hf2_,wfh[2][2],AN); AN=mfma16(hf3_,wfh[2][3],AN); }

#define GATES(G, AN, hp, grp, nxt) { \
  _Pragma("unroll") \
  for (int r_=0;r_<4;++r_){ \
    float rr_=sigm(G[0][r_]); \
    float zz_=sigm(G[1][r_]); \
    float nn_=tanh_f(G[2][r_]+rr_*AN[r_]); \
    float hv_=(1.0f-zz_)*nn_+zz_*hp[r_]; hp[r_]=hv_; \
    hlds[nxt][grp][lq*4+r_][w*16+lr]=f2bf(hv_); } }

__global__ __launch_bounds__(512, 2) void k_gru(int phase,
    const u16* __restrict__ mon_xT, const u16* __restrict__ vis_org,
    u16* __restrict__ hin2T, u16* __restrict__ h2,
    const u16* __restrict__ mWih, const float* __restrict__ mbih,
    const u16* __restrict__ mWhh, const float* __restrict__ mbhh,
    const u16* __restrict__ vWih, const float* __restrict__ vbih,
    const u16* __restrict__ vWhh, const float* __restrict__ vbhh){
  int s = blockIdx.y, bx = blockIdx.x;
  int T, oMode, g0, g1; const u16* A; size_t rstride; u16* ho;
  const u16 *Wi, *Wh; const float *biP, *bhP;
  if (phase == 0 && s < 5){
    T = 32; oMode = 0; g0 = 2*bx; g1 = g0 + 1;
    if (s < 2){ A = mon_xT + (size_t)s*24576*128; rstride = 768*128; }
    else      { A = vis_org + (size_t)(s-2)*768*128; rstride = 0; }
    Wi = mWih + (size_t)s*49152; Wh = mWhh + (size_t)s*49152;
    biP = mbih + (size_t)s*384;  bhP = mbhh + (size_t)s*384;
    int slot = (0x32140u >> (4*s)) & 15;
    ho = hin2T + (size_t)slot*768*128;
  } else {
    if (bx >= 2) return;
    T = 16; oMode = 1; g0 = bx ? 2 : 0; g1 = bx ? 2 : 1;
    A = hin2T + (size_t)s*768*128; rstride = 48*128;
    int vi = (phase == 0) ? s : ((0x6514320u >> (4*s)) & 15);
    Wi = vWih + (size_t)vi*49152; Wh = vWhh + (size_t)vi*49152;
    biP = vbih + (size_t)vi*384;  bhP = vbhh + (size_t)vi*384;
    ho = h2 + (size_t)s*48*128;
  }

  int w = threadIdx.x >> 6, l = threadIdx.x & 63;
  int lr = l & 15, lq = l >> 4;

  // wave w owns gate-col-chunk w*16..+16 of r,z,n (tiles w, 8+w, 16+w)
  bf8 wfh[3][4];
  float bs0_, bs1_, bin_, bhn_;
  #pragma unroll
  for (int j = 0; j < 3; ++j){
    int colb = (w + 8*j)*16;
    const u16* wph = Wh + (size_t)(colb + lr)*128 + lq*8;
    #pragma unroll
    for (int kt = 0; kt < 4; ++kt) wfh[j][kt] = *(const bf8*)(wph + kt*32);
  }
  bs0_ = biP[w*16 + lr] + bhP[w*16 + lr];
  bs1_ = biP[(8+w)*16 + lr] + bhP[(8+w)*16 + lr];
  bin_ = biP[(16+w)*16 + lr];
  bhn_ = bhP[(16+w)*16 + lr];

  const u16* apA = A + (size_t)(g0*16 + lr)*128 + lq*8;
  const u16* apB = A + (size_t)(g1*16 + lr)*128 + lq*8;
  __shared__ u16 hlds[2][2][16][132];   // 66-dword stride: conflict-free b128
  float hpA[4] = {0.f,0.f,0.f,0.f}, hpB[4] = {0.f,0.f,0.f,0.f};
  int cur = 0;

  if (rstride){
    bf8 wfi[3][4];
    #pragma unroll
    for (int j = 0; j < 3; ++j){
      int colb = (w + 8*j)*16;
      const u16* wpi = Wi + (size_t)(colb + lr)*128 + lq*8;
      #pragma unroll
      for (int kt = 0; kt < 4; ++kt) wfi[j][kt] = *(const bf8*)(wpi + kt*32);
    }
    bf8 SA[4], SB[4]; f4 GA[3], GB[3], ANA, ANB;
    ALOAD(SA, apA, 0); ALOAD(SB, apB, 0);
    GIMM(GA, SA); GIMM(GB, SB);                 // gi(0)
    ALOAD(SA, apA, 1); ALOAD(SB, apB, 1);
    { f4 an0={bhn_,bhn_,bhn_,bhn_}; ANA=an0; ANB=an0; }
    GATES(GA, ANA, hpA, 0, 1); GATES(GB, ANB, hpB, 1, 1);   // t=0 (h0=0)
    GIMM(GA, SA); GIMM(GB, SB);                 // gi(1)
    ALOAD(SA, apA, 2); ALOAD(SB, apB, 2);
    BARRIER(); cur = 1;
    for (int t = 1; t < T; ++t){
      GH(GA, ANA, 0); GH(GB, ANB, 1);
      int nxt = cur ^ 1;
      GATES(GA, ANA, hpA, 0, nxt); GATES(GB, ANB, hpB, 1, nxt);
      if (t+1 < T){
        GIMM(GA, SA); GIMM(GB, SB);             // gi(t+1)
        ALOAD(SA, apA, t+2); ALOAD(SB, apB, t+2);
      }
      BARRIER(); cur = nxt;
    }
  } else {
    f4 CA[3], CB[3], GA[3], GB[3], ANA, ANB;
    {
      bf8 wfi[3][4];
      #pragma unroll
      for (int j = 0; j < 3; ++j){
        int colb = (w + 8*j)*16;
        const u16* wpi = Wi + (size_t)(colb + lr)*128 + lq*8;
        #pragma unroll
        for (int kt = 0; kt < 4; ++kt) wfi[j][kt] = *(const bf8*)(wpi + kt*32);
      }
      bf8 SA[4], SB[4];
      ALOAD(SA, apA, 0); ALOAD(SB, apB, 0);
      GIMM(CA, SA); GIMM(CB, SB);               // constant gi
    }
    GA[0]=CA[0]; GA[1]=CA[1]; GA[2]=CA[2];
    GB[0]=CB[0]; GB[1]=CB[1]; GB[2]=CB[2];
    { f4 an0={bhn_,bhn_,bhn_,bhn_}; ANA=an0; ANB=an0; }
    GATES(GA, ANA, hpA, 0, 1); GATES(GB, ANB, hpB, 1, 1);   // t=0
    BARRIER(); cur = 1;
    for (int t = 1; t < T; ++t){
      GA[0]=CA[0]; GA[1]=CA[1]; GA[2]=CA[2];
      GB[0]=CB[0]; GB[1]=CB[1]; GB[2]=CB[2];
      GH(GA, ANA, 0); GH(GB, ANB, 1);
      int nxt = cur ^ 1;
      GATES(GA, ANA, hpA, 0, nxt); GATES(GB, ANB, hpB, 1, nxt);
      BARRIER(); cur = nxt;
    }
  }

  if (oMode == 0){
    #pragma unroll
    for (int r = 0; r < 4; ++r){
      ho[((size_t)(lq*4+r)*48 + g0)*128 + w*16 + lr] = f2bf(hpA[r]);
      ho[((size_t)(lq*4+r)*48 + g1)*128 + w*16 + lr] = f2bf(hpB[r]);
    }
  } else {
    #pragma unroll
    for (int r = 0; r < 4; ++r){
      ho[((size_t)(g0*16 + lq*4 + r))*128 + w*16 + lr] = f2bf(hpA[r]);
      ho[((size_t)(g1*16 + lq*4 + r))*128 + w*16 + lr] = f2bf(hpB[r]);
    }
  }
}

// ================= final projection =================
__global__ __launch_bounds__(256) void k_final(const u16* __restrict__ h2,
                                               const float* __restrict__ W,
                                               const float* __restrict__ Bias,
                                               float* __restrict__ out){
  int b = blockIdx.x, t = threadIdx.x;
  __shared__ float emb[896];
  for (int i = t; i < 896; i += 256){
    int j = i >> 7, d = i & 127;
    float v = bf2f(h2[((size_t)j*48 + b)*128 + d]);
    if (j >= 1 && j <= 3) v *= 2.0f;   // slots 1..3 appear twice in reference sum
    emb[i] = fmaxf(v, 0.f);
  }
  __syncthreads();
  float acc = Bias[t];
  const float* wp = W + (size_t)t*896;
  for (int i = 0; i < 896; i += 8){
    float4 w0 = *(const float4*)(wp + i);
    float4 w1 = *(const float4*)(wp + i + 4);
    acc += w0.x*emb[i]   + w0.y*emb[i+1] + w0.z*emb[i+2] + w0.w*emb[i+3];
    acc += w1.x*emb[i+4] + w1.y*emb[i+5] + w1.z*emb[i+6] + w1.w*emb[i+7];
  }
  out[(size_t)b*256 + t] = acc;
}

extern "C" void kernel_launch(void* const* d_in, const int* in_sizes, int n_in,
                              void* d_out, int out_size, void* d_ws, size_t ws_size,
                              hipStream_t stream){
  const int*   visit_ids   = (const int*)d_in[0];
  const int*   mon_ids     = (const int*)d_in[1];
  const float* weight_vals = (const float*)d_in[2];
  const float* age_vals    = (const float*)d_in[3];
  const float* emb_visit   = (const float*)d_in[4];
  const float* emb_mon     = (const float*)d_in[5];
  const float* mgru_Wih    = (const float*)d_in[6];
  const float* mgru_Whh    = (const float*)d_in[7];
  const float* mgru_bih    = (const float*)d_in[8];
  const float* mgru_bhh    = (const float*)d_in[9];
  const float* vgru_Wih    = (const float*)d_in[10];
  const float* vgru_Whh    = (const float*)d_in[11];
  const float* vgru_bih    = (const float*)d_in[12];
  const float* vgru_bhh    = (const float*)d_in[13];
  const float* fc_w_w      = (const float*)d_in[14];
  const float* fc_w_b      = (const float*)d_in[15];
  const float* fc_a_w      = (const float*)d_in[16];
  const float* fc_a_b      = (const float*)d_in[17];
  const float* fc_out_w    = (const float*)d_in[18];
  const float* fc_out_b    = (const float*)d_in[19];

  char* ws = (char*)d_ws;
  size_t o = 0;
  u16* mWih_b  = (u16*)(ws+o); o += 5ull*384*128*2;
  u16* mWhh_b  = (u16*)(ws+o); o += 5ull*384*128*2;
  u16* vWih_b  = (u16*)(ws+o); o += 7ull*384*128*2;
  u16* vWhh_b  = (u16*)(ws+o); o += 7ull*384*128*2;
  u16* embm_b  = (u16*)(ws+o); o += 4ull*1000*128*2;
  u16* embv_b  = (u16*)(ws+o); o += 3ull*2000*128*2;
  u16* mon_xT  = (u16*)(ws+o); o += 2ull*24576*128*2;    // [p][m*768+bv][128]
  u16* vis_org = (u16*)(ws+o); o += 3ull*768*128*2;
  u16* hin2T   = (u16*)(ws+o); o += 7ull*768*128*2;      // [slot][v*48+b][128]
  u16* h2      = (u16*)(ws+o); o += 7ull*48*128*2;       // ~18 MB total

  k_prep<<<2402, 256, 0, stream>>>(mgru_Wih, mgru_Whh, vgru_Wih, vgru_Whh, emb_mon, emb_visit,
                                   mWih_b, mWhh_b, vWih_b, vWhh_b, embm_b, embv_b);
  k_bags<<<dim3(3072,3), 256, 0, stream>>>(visit_ids, mon_ids, embv_b, embm_b,
      weight_vals, age_vals, fc_w_w, fc_w_b, fc_a_w, fc_a_b,
      mon_xT, vis_org, hin2T);
  // phase 0: monitor-level streams 0..4 + visit-level streams 5,6
  k_gru<<<dim3(24,7), 512, 0, stream>>>(0, mon_xT, vis_org, hin2T, h2,
      mWih_b, mgru_bih, mWhh_b, mgru_bhh, vWih_b, vgru_bih, vWhh_b, vgru_bhh);
  // phase 1: visit-level streams 0..4
  k_gru<<<dim3(2,5), 512, 0, stream>>>(1, mon_xT, vis_org, hin2T, h2,
      mWih_b, mgru_bih, mWhh_b, mgru_bhh, vWih_b, vgru_bih, vWhh_b, vgru_bhh);
  k_final<<<48, 256, 0, stream>>>(h2, fc_out_w, fc_out_b, (float*)d_out);
}

// Round 9
// 142.238 us; speedup vs baseline: 1.3665x; 1.2017x over previous
//
#include <hip/hip_runtime.h>
#include <stdint.h>

// PersonalMed on MI355X. B=48,V=16,M=32,C=48,CM=8,D=128,OUT=256. f32 in/out.
// Round-9: re-converge on the round-6 GRU core (best measured: 45us phase-0,
// 1 chain per 8-wave block) + consolidated front-end (r8) + stream 5,6 fold.
// Micro-fix vs r6: GIMM/ALOAD issued BETWEEN the h ds_writes and the
// lgkmcnt(0)+s_barrier, so their issue overlaps the ds_write completion.
// Lesson from r7/r8: packing 2 chains per wave ~doubles step time (per-step
// wall tracks per-wave serial stream) -- 1 chain/block is the right shape.

typedef unsigned short u16;
typedef uint32_t u32;
typedef short bf8 __attribute__((ext_vector_type(8)));   // 8 bf16 = 4 VGPRs
typedef float f4 __attribute__((ext_vector_type(4)));

static __device__ __forceinline__ float bf2f(u16 b){ u32 u=((u32)b)<<16; float f; __builtin_memcpy(&f,&u,4); return f; }
static __device__ __forceinline__ u16 f2bf(float f){ u32 u; __builtin_memcpy(&u,&f,4); u32 r=(u+0x7fffu+((u>>16)&1u))>>16; return (u16)r; }
static __device__ __forceinline__ float bflo(u32 u){ u32 x=u<<16; float f; __builtin_memcpy(&f,&x,4); return f; }
static __device__ __forceinline__ float bfhi(u32 u){ u32 x=u&0xffff0000u; float f; __builtin_memcpy(&f,&x,4); return f; }
static __device__ __forceinline__ f4 mfma16(bf8 a, bf8 b, f4 c){ return __builtin_amdgcn_mfma_f32_16x16x32_bf16(a,b,c,0,0,0); }

#if __has_builtin(__builtin_amdgcn_exp2f)
static __device__ __forceinline__ float fexp2(float x){ return __builtin_amdgcn_exp2f(x); }
#else
static __device__ __forceinline__ float fexp2(float x){ float r; asm volatile("v_exp_f32 %0, %1" : "=v"(r) : "v"(x)); return r; }
#endif
#if __has_builtin(__builtin_amdgcn_rcpf)
static __device__ __forceinline__ float frcp(float x){ return __builtin_amdgcn_rcpf(x); }
#else
static __device__ __forceinline__ float frcp(float x){ float r; asm volatile("v_rcp_f32 %0, %1" : "=v"(r) : "v"(x)); return r; }
#endif
#define LOG2E 1.44269504089f
static __device__ __forceinline__ float sigm(float x){ return frcp(1.0f + fexp2(-LOG2E*x)); }
static __device__ __forceinline__ float tanh_f(float x){ return 1.0f - 2.0f*frcp(1.0f + fexp2((2.0f*LOG2E)*x)); }

// ================= k_prep: f32->bf16 (GRU weights + emb_mon + emb_visit) =================
// flat float4 ranges: mWih 61440 | mWhh 61440 | vWih 86016 | vWhh 86016 | embm 128000 | embv 192000
__global__ __launch_bounds__(256) void k_prep(
    const float* __restrict__ s0, const float* __restrict__ s1,
    const float* __restrict__ s2, const float* __restrict__ s3,
    const float* __restrict__ s4, const float* __restrict__ s5,
    u16* __restrict__ d0, u16* __restrict__ d1, u16* __restrict__ d2,
    u16* __restrict__ d3, u16* __restrict__ d4, u16* __restrict__ d5){
  int i = blockIdx.x*256 + threadIdx.x;
  const float* s; u16* d; int off;
  if      (i < 61440)  { s=s0; d=d0; off=i; }
  else if (i < 122880) { s=s1; d=d1; off=i-61440; }
  else if (i < 208896) { s=s2; d=d2; off=i-122880; }
  else if (i < 294912) { s=s3; d=d3; off=i-208896; }
  else if (i < 422912) { s=s4; d=d4; off=i-294912; }
  else if (i < 614912) { s=s5; d=d5; off=i-422912; }
  else return;
  float4 v = *(const float4*)(s + (size_t)off*4);
  ushort4 o = { f2bf(v.x), f2bf(v.y), f2bf(v.z), f2bf(v.w) };
  *(ushort4*)(d + (size_t)off*4) = o;
}

// ================= k_bags: mon bag + visit bags + weight/age (bf16 tables) =================
// grid (3072,3) block 256. y=0/1: mon p=y, 8 rows/block. y=2: x<1152 visit bags
// (2 rows/block of 2304), 1152<=x<1920 weight/age (2 rows/block of 1536).
__global__ __launch_bounds__(256) void k_bags(const int* __restrict__ vids, const int* __restrict__ mids,
    const u16* __restrict__ embv_b, const u16* __restrict__ embm_b,
    const float* __restrict__ wv, const float* __restrict__ av,
    const float* __restrict__ ww, const float* __restrict__ wb,
    const float* __restrict__ aw, const float* __restrict__ ab,
    u16* __restrict__ mon_xT, u16* __restrict__ vis_org, u16* __restrict__ hin2T){
  int y = blockIdx.y;
  if (y < 2){
    int p = y;
    int rid = threadIdx.x >> 5, lane32 = threadIdx.x & 31, d0 = lane32*4;
    __shared__ int ids[8][16];
    if (threadIdx.x < 128){
      int rr = threadIdx.x >> 4, c = threadIdx.x & 15;
      int f = 2*p + (c>>3), cm = c & 7;
      ids[rr][c] = mids[((size_t)f*24576 + (size_t)blockIdx.x*8 + rr)*8 + cm];
    }
    __syncthreads();
    const u16* e1 = embm_b + (size_t)(2*p)*1000*128;
    const u16* e2 = embm_b + (size_t)(2*p+1)*1000*128;
    float a0=0.f,a1=0.f,a2=0.f,a3=0.f;
    #pragma unroll
    for (int c = 0; c < 8; ++c){
      int i1 = ids[rid][c], i2 = ids[rid][8+c];
      if (i1 && i2){
        uint2 a = *(const uint2*)(e1 + (size_t)i1*128 + d0);
        uint2 b = *(const uint2*)(e2 + (size_t)i2*128 + d0);
        a0 += bflo(a.x)*bflo(b.x); a1 += bfhi(a.x)*bfhi(b.x);
        a2 += bflo(a.y)*bflo(b.y); a3 += bfhi(a.y)*bfhi(b.y);
      }
    }
    size_t nm = (size_t)blockIdx.x*8 + rid;
    int bv = (int)(nm >> 5), m = (int)(nm & 31);
    ushort4 o = { f2bf(a0), f2bf(a1), f2bf(a2), f2bf(a3) };
    *(ushort4*)(mon_xT + (size_t)p*24576*128 + ((size_t)m*768 + bv)*128 + d0) = o;
  } else {
    int x = blockIdx.x;
    int sub = threadIdx.x >> 7, d = threadIdx.x & 127;
    if (x < 1152){
      __shared__ int ids[2][48];
      int row = x*2 + sub;
      int k = row / 768, bv = row - k*768;
      if (d < 48) ids[sub][d] = vids[((size_t)k*768 + bv)*48 + d];
      __syncthreads();
      const u16* eb = embv_b + (size_t)k*2000*128;
      float acc = 0.f;
      #pragma unroll 4
      for (int c = 0; c < 48; ++c){ int id = ids[sub][c]; if (id) acc += bf2f(eb[(size_t)id*128 + d]); }
      vis_org[((size_t)k*768 + bv)*128 + d] = f2bf(acc);
    } else if (x < 1920){
      int grow = (x - 1152)*2 + sub;
      int sidx = grow >= 768 ? 1 : 0;
      int row = grow - sidx*768;
      const float* vals = sidx ? av : wv;
      const float* wgt  = sidx ? aw : ww;
      const float* bias = sidx ? ab : wb;
      float v = vals[row];
      float h = (v != 0.f) ? (v * wgt[d] + bias[d]) : 0.f;
      int b = row >> 4, vv = row & 15;
      hin2T[((size_t)(5+sidx)*768 + (size_t)vv*48 + b)*128 + d] = f2bf(h);
    }
  }
}

// ================= fused GRU (r6 core, 1 chain per 8-wave block) =================
// phase 0: grid (48,7).
//   s<2 : T=32, A=mon_xT[s] (rstride=768*128), mgru[s], out hin2T[slot 0x32140].
//   s=2..4: T=32, A=vis_org[s-2] (rstride=0, const gi), mgru[s], out slot.
//   s=5,6 (x<3): T=16, A=hin2T[s] (rstride=48*128), vgru[s], out h2[s].
// phase 1: grid (3,5): visit streams s=0..4, vi=0x6514320 nibble, out h2[s].

#define BARRIER() asm volatile("s_waitcnt lgkmcnt(0)\n\ts_barrier" ::: "memory")

#define ALOAD(S, tt) { int t_=(tt); if (t_>=T) t_=0; \
  const u16* p_ = ap + (size_t)t_*rstride; \
  S[0]=*(const bf8*)(p_); S[1]=*(const bf8*)(p_+32); \
  S[2]=*(const bf8*)(p_+64); S[3]=*(const bf8*)(p_+96); }

#define GIMM(G0,G1,G2,S) { \
  f4 t0_={biv[0],biv[0],biv[0],biv[0]}; G0=t0_; \
  f4 t1_={biv[1],biv[1],biv[1],biv[1]}; G1=t1_; \
  f4 t2_={biv[2],biv[2],biv[2],biv[2]}; G2=t2_; \
  G0=mfma16(S[0],wfi[0][0],G0); G0=mfma16(S[1],wfi[0][1],G0); \
  G0=mfma16(S[2],wfi[0][2],G0); G0=mfma16(S[3],wfi[0][3],G0); \
  G1=mfma16(S[0],wfi[1][0],G1); G1=mfma16(S[1],wfi[1][1],G1); \
  G1=mfma16(S[2],wfi[1][2],G1); G1=mfma16(S[3],wfi[1][3],G1); \
  G2=mfma16(S[0],wfi[2][0],G2); G2=mfma16(S[1],wfi[2][1],G2); \
  G2=mfma16(S[2],wfi[2][2],G2); G2=mfma16(S[3],wfi[2][3],G2); }

// declares a0_,a1_,a2_ (gh accumulators) + reads hf from hlds[cur]
#define GHRD() \
  bf8 hf0_=*(const bf8*)&hlds[cur][lr][lq*8]; \
  bf8 hf1_=*(const bf8*)&hlds[cur][lr][32+lq*8]; \
  bf8 hf2_=*(const bf8*)&hlds[cur][lr][64+lq*8]; \
  bf8 hf3_=*(const bf8*)&hlds[cur][lr][96+lq*8]; \
  f4 a0_={bhv[0],bhv[0],bhv[0],bhv[0]}; \
  f4 a1_={bhv[1],bhv[1],bhv[1],bhv[1]}; \
  f4 a2_={bhv[2],bhv[2],bhv[2],bhv[2]}; \
  a0_=mfma16(hf0_,wfh[0][0],a0_); a0_=mfma16(hf1_,wfh[0][1],a0_); \
  a0_=mfma16(hf2_,wfh[0][2],a0_); a0_=mfma16(hf3_,wfh[0][3],a0_); \
  a1_=mfma16(hf0_,wfh[1][0],a1_); a1_=mfma16(hf1_,wfh[1][1],a1_); \
  a1_=mfma16(hf2_,wfh[1][2],a1_); a1_=mfma16(hf3_,wfh[1][3],a1_); \
  a2_=mfma16(hf0_,wfh[2][0],a2_); a2_=mfma16(hf1_,wfh[2][1],a2_); \
  a2_=mfma16(hf2_,wfh[2][2],a2_); a2_=mfma16(hf3_,wfh[2][3],a2_);

// consume G + a*_ -> h_{t+1}; write LDS. NO barrier (placed by caller).
#define GATES_NB(G0,G1,G2) { int nxt_=cur^1; \
  _Pragma("unroll") \
  for (int r=0;r<4;++r){ \
    float rr_=sigm(G0[r]+a0_[r]); \
    float zz_=sigm(G1[r]+a1_[r]); \
    float nn_=tanh_f(G2[r]+rr_*a2_[r]); \
    float hv_=(1.0f-zz_)*nn_+zz_*hp[r]; hp[r]=hv_; \
    hlds[nxt_][lq*4+r][w*16+lr]=f2bf(hv_); } }

// pipelined step: consume gi(t) from G; GIMM rebuilds G = gi(t+2) from SN and
// ALOAD refills SN with A(t+4) -- both issued BETWEEN the h ds_writes and the
// lgkmcnt(0)+barrier so their issue overlaps the write completion.
#define STEPB(G0,G1,G2,SN,tt) { \
  GHRD(); \
  GATES_NB(G0,G1,G2); \
  if ((tt)+2 < T){ GIMM(G0,G1,G2,SN); } \
  ALOAD(SN,(tt)+4); \
  BARRIER(); cur ^= 1; }

__global__ __launch_bounds__(512, 2) void k_gru(int phase,
    const u16* __restrict__ mon_xT, const u16* __restrict__ vis_org,
    u16* __restrict__ hin2T, u16* __restrict__ h2,
    const u16* __restrict__ mWih, const float* __restrict__ mbih,
    const u16* __restrict__ mWhh, const float* __restrict__ mbhh,
    const u16* __restrict__ vWih, const float* __restrict__ vbih,
    const u16* __restrict__ vWhh, const float* __restrict__ vbhh){
  int s = blockIdx.y, g = blockIdx.x;
  const u16* A; size_t rstride; int T, oMode; u16* ho;
  const u16 *Wi, *Wh; const float *bi2, *bh2;
  if (phase == 0 && s < 5){
    T = 32; oMode = 0;
    if (s < 2){ A = mon_xT + (size_t)s*24576*128; rstride = 768*128; }
    else      { A = vis_org + (size_t)(s-2)*768*128; rstride = 0; }
    Wi = mWih + (size_t)s*49152; Wh = mWhh + (size_t)s*49152;
    bi2 = mbih + (size_t)s*384;  bh2 = mbhh + (size_t)s*384;
    int slot = (0x32140u >> (4*s)) & 15;
    ho = hin2T + (size_t)slot*768*128;
  } else {
    if (g >= 3) return;
    T = 16; oMode = 1;
    A = hin2T + (size_t)s*768*128; rstride = 48*128;
    int vi = (0x6514320u >> (4*s)) & 15;
    Wi = vWih + (size_t)vi*49152; Wh = vWhh + (size_t)vi*49152;
    bi2 = vbih + (size_t)vi*384;  bh2 = vbhh + (size_t)vi*384;
    ho = h2 + (size_t)s*48*128;
  }

  int w = threadIdx.x >> 6, l = threadIdx.x & 63;
  int lr = l & 15, lq = l >> 4;

  // wave w owns gate-col-chunk w*16..+16 of r,z,n (tiles w, 8+w, 16+w)
  bf8 wfi[3][4], wfh[3][4]; float biv[3], bhv[3];
  #pragma unroll
  for (int j = 0; j < 3; ++j){
    int colb = (w + 8*j)*16;
    const u16* wpi = Wi + (size_t)(colb + lr)*128 + lq*8;
    const u16* wph = Wh + (size_t)(colb + lr)*128 + lq*8;
    #pragma unroll
    for (int kt = 0; kt < 4; ++kt){
      wfi[j][kt] = *(const bf8*)(wpi + kt*32);
      wfh[j][kt] = *(const bf8*)(wph + kt*32);
    }
    biv[j] = bi2[colb + lr];
    bhv[j] = bh2[colb + lr];
  }

  const u16* ap = A + (size_t)(g*16 + lr)*128 + lq*8;
  __shared__ u16 hlds[2][16][132];   // 66-dword row stride: conflict-free b128
  float hp[4] = {0.f,0.f,0.f,0.f};
  int cur = 0;

  if (rstride){
    bf8 S0[4], S1[4];
    f4 gE0,gE1,gE2, gO0,gO1,gO2;
    ALOAD(S0,0); ALOAD(S1,1);
    GIMM(gE0,gE1,gE2,S0); ALOAD(S0,2);      // gi(0); A(2) in flight
    GIMM(gO0,gO1,gO2,S1); ALOAD(S1,3);      // gi(1); A(3) in flight
    { // t=0: gh = bhh (h0 = 0)
      f4 a0_={bhv[0],bhv[0],bhv[0],bhv[0]};
      f4 a1_={bhv[1],bhv[1],bhv[1],bhv[1]};
      f4 a2_={bhv[2],bhv[2],bhv[2],bhv[2]};
      GATES_NB(gE0,gE1,gE2);
      GIMM(gE0,gE1,gE2,S0); ALOAD(S0,4);    // gi(2); A(4) in flight
      BARRIER(); cur ^= 1;
    }
    STEPB(gO0,gO1,gO2,S1,1);                // t=1: consume gi(1), build gi(3)
    for (int t = 2; t < T; t += 2){
      STEPB(gE0,gE1,gE2,S0,t);
      STEPB(gO0,gO1,gO2,S1,t+1);
    }
  } else {
    bf8 S0[4];
    f4 gE0,gE1,gE2;
    ALOAD(S0,0);
    GIMM(gE0,gE1,gE2,S0);                   // constant gi, computed once
    { // t=0
      f4 a0_={bhv[0],bhv[0],bhv[0],bhv[0]};
      f4 a1_={bhv[1],bhv[1],bhv[1],bhv[1]};
      f4 a2_={bhv[2],bhv[2],bhv[2],bhv[2]};
      GATES_NB(gE0,gE1,gE2);
      BARRIER(); cur ^= 1;
    }
    for (int t = 1; t < T; ++t){
      GHRD();
      GATES_NB(gE0,gE1,gE2);
      BARRIER(); cur ^= 1;
    }
  }

  if (oMode == 0){
    #pragma unroll
    for (int r = 0; r < 4; ++r)
      ho[((size_t)(lq*4+r)*48 + g)*128 + w*16 + lr] = f2bf(hp[r]);
  } else {
    #pragma unroll
    for (int r = 0; r < 4; ++r)
      ho[((size_t)(g*16 + lq*4 + r))*128 + w*16 + lr] = f2bf(hp[r]);
  }
}

// ================= final projection =================
__global__ __launch_bounds__(256) void k_final(const u16* __restrict__ h2,
                                               const float* __restrict__ W,
                                               const float* __restrict__ Bias,
                                               float* __restrict__ out){
  int b = blockIdx.x, t = threadIdx.x;
  __shared__ float emb[896];
  for (int i = t; i < 896; i += 256){
    int j = i >> 7, d = i & 127;
    float v = bf2f(h2[((size_t)j*48 + b)*128 + d]);
    if (j >= 1 && j <= 3) v *= 2.0f;   // slots 1..3 appear twice in reference sum
    emb[i] = fmaxf(v, 0.f);
  }
  __syncthreads();
  float acc = Bias[t];
  const float* wp = W + (size_t)t*896;
  for (int i = 0; i < 896; i += 8){
    float4 w0 = *(const float4*)(wp + i);
    float4 w1 = *(const float4*)(wp + i + 4);
    acc += w0.x*emb[i]   + w0.y*emb[i+1] + w0.z*emb[i+2] + w0.w*emb[i+3];
    acc += w1.x*emb[i+4] + w1.y*emb[i+5] + w1.z*emb[i+6] + w1.w*emb[i+7];
  }
  out[(size_t)b*256 + t] = acc;
}

extern "C" void kernel_launch(void* const* d_in, const int* in_sizes, int n_in,
                              void* d_out, int out_size, void* d_ws, size_t ws_size,
                              hipStream_t stream){
  const int*   visit_ids   = (const int*)d_in[0];
  const int*   mon_ids     = (const int*)d_in[1];
  const float* weight_vals = (const float*)d_in[2];
  const float* age_vals    = (const float*)d_in[3];
  const float* emb_visit   = (const float*)d_in[4];
  const float* emb_mon     = (const float*)d_in[5];
  const float* mgru_Wih    = (const float*)d_in[6];
  const float* mgru_Whh    = (const float*)d_in[7];
  const float* mgru_bih    = (const float*)d_in[8];
  const float* mgru_bhh    = (const float*)d_in[9];
  const float* vgru_Wih    = (const float*)d_in[10];
  const float* vgru_Whh    = (const float*)d_in[11];
  const float* vgru_bih    = (const float*)d_in[12];
  const float* vgru_bhh    = (const float*)d_in[13];
  const float* fc_w_w      = (const float*)d_in[14];
  const float* fc_w_b      = (const float*)d_in[15];
  const float* fc_a_w      = (const float*)d_in[16];
  const float* fc_a_b      = (const float*)d_in[17];
  const float* fc_out_w    = (const float*)d_in[18];
  const float* fc_out_b    = (const float*)d_in[19];

  char* ws = (char*)d_ws;
  size_t o = 0;
  u16* mWih_b  = (u16*)(ws+o); o += 5ull*384*128*2;
  u16* mWhh_b  = (u16*)(ws+o); o += 5ull*384*128*2;
  u16* vWih_b  = (u16*)(ws+o); o += 7ull*384*128*2;
  u16* vWhh_b  = (u16*)(ws+o); o += 7ull*384*128*2;
  u16* embm_b  = (u16*)(ws+o); o += 4ull*1000*128*2;
  u16* embv_b  = (u16*)(ws+o); o += 3ull*2000*128*2;
  u16* mon_xT  = (u16*)(ws+o); o += 2ull*24576*128*2;    // [p][m*768+bv][128]
  u16* vis_org = (u16*)(ws+o); o += 3ull*768*128*2;
  u16* hin2T   = (u16*)(ws+o); o += 7ull*768*128*2;      // [slot][v*48+b][128]
  u16* h2      = (u16*)(ws+o); o += 7ull*48*128*2;       // ~18 MB total

  k_prep<<<2402, 256, 0, stream>>>(mgru_Wih, mgru_Whh, vgru_Wih, vgru_Whh, emb_mon, emb_visit,
                                   mWih_b, mWhh_b, vWih_b, vWhh_b, embm_b, embv_b);
  k_bags<<<dim3(3072,3), 256, 0, stream>>>(visit_ids, mon_ids, embv_b, embm_b,
      weight_vals, age_vals, fc_w_w, fc_w_b, fc_a_w, fc_a_b,
      mon_xT, vis_org, hin2T);
  // phase 0: monitor-level streams 0..4 (48 blocks each) + visit streams 5,6 (3 blocks)
  k_gru<<<dim3(48,7), 512, 0, stream>>>(0, mon_xT, vis_org, hin2T, h2,
      mWih_b, mgru_bih, mWhh_b, mgru_bhh, vWih_b, vgru_bih, vWhh_b, vgru_bhh);
  // phase 1: visit-level streams 0..4
  k_gru<<<dim3(3,5), 512, 0, stream>>>(1, mon_xT, vis_org, hin2T, h2,
      mWih_b, mgru_bih, mWhh_b, mgru_bhh, vWih_b, vgru_bih, vWhh_b, vgru_bhh);
  k_final<<<48, 256, 0, stream>>>(h2, fc_out_w, fc_out_b, (float*)d_out);
}

// Round 10
// 140.381 us; speedup vs baseline: 1.3846x; 1.0132x over previous
//
#include <hip/hip_runtime.h>
#include <stdint.h>

// PersonalMed on MI355X. B=48,V=16,M=32,C=48,CM=8,D=128,OUT=256. f32 in/out.
// Round-10: r6's measured-best step schedule restored (GH -> gates+ds_write+
// barrier -> GIMM -> ALOAD; post-barrier GIMM overlaps next ds_read latency)
// + r8's verified GH-merge: h@Whh chained into gi accumulators via the MFMA
// C-operand (r/z biases pre-summed; n-gate keeps separate AN).
// Lessons: pre-barrier work is paid xT (r9, +11us); >1 chain/wave ~doubles
// step time (r7/r8); IEEE div in gates was the r2-r5 60us floor (r6).

typedef unsigned short u16;
typedef uint32_t u32;
typedef short bf8 __attribute__((ext_vector_type(8)));   // 8 bf16 = 4 VGPRs
typedef float f4 __attribute__((ext_vector_type(4)));

static __device__ __forceinline__ float bf2f(u16 b){ u32 u=((u32)b)<<16; float f; __builtin_memcpy(&f,&u,4); return f; }
static __device__ __forceinline__ u16 f2bf(float f){ u32 u; __builtin_memcpy(&u,&f,4); u32 r=(u+0x7fffu+((u>>16)&1u))>>16; return (u16)r; }
static __device__ __forceinline__ float bflo(u32 u){ u32 x=u<<16; float f; __builtin_memcpy(&f,&x,4); return f; }
static __device__ __forceinline__ float bfhi(u32 u){ u32 x=u&0xffff0000u; float f; __builtin_memcpy(&f,&x,4); return f; }
static __device__ __forceinline__ f4 mfma16(bf8 a, bf8 b, f4 c){ return __builtin_amdgcn_mfma_f32_16x16x32_bf16(a,b,c,0,0,0); }

#if __has_builtin(__builtin_amdgcn_exp2f)
static __device__ __forceinline__ float fexp2(float x){ return __builtin_amdgcn_exp2f(x); }
#else
static __device__ __forceinline__ float fexp2(float x){ float r; asm volatile("v_exp_f32 %0, %1" : "=v"(r) : "v"(x)); return r; }
#endif
#if __has_builtin(__builtin_amdgcn_rcpf)
static __device__ __forceinline__ float frcp(float x){ return __builtin_amdgcn_rcpf(x); }
#else
static __device__ __forceinline__ float frcp(float x){ float r; asm volatile("v_rcp_f32 %0, %1" : "=v"(r) : "v"(x)); return r; }
#endif
#define LOG2E 1.44269504089f
static __device__ __forceinline__ float sigm(float x){ return frcp(1.0f + fexp2(-LOG2E*x)); }
static __device__ __forceinline__ float tanh_f(float x){ return 1.0f - 2.0f*frcp(1.0f + fexp2((2.0f*LOG2E)*x)); }

// ================= k_prep: f32->bf16 (GRU weights + emb_mon + emb_visit) =================
// flat float4 ranges: mWih 61440 | mWhh 61440 | vWih 86016 | vWhh 86016 | embm 128000 | embv 192000
__global__ __launch_bounds__(256) void k_prep(
    const float* __restrict__ s0, const float* __restrict__ s1,
    const float* __restrict__ s2, const float* __restrict__ s3,
    const float* __restrict__ s4, const float* __restrict__ s5,
    u16* __restrict__ d0, u16* __restrict__ d1, u16* __restrict__ d2,
    u16* __restrict__ d3, u16* __restrict__ d4, u16* __restrict__ d5){
  int i = blockIdx.x*256 + threadIdx.x;
  const float* s; u16* d; int off;
  if      (i < 61440)  { s=s0; d=d0; off=i; }
  else if (i < 122880) { s=s1; d=d1; off=i-61440; }
  else if (i < 208896) { s=s2; d=d2; off=i-122880; }
  else if (i < 294912) { s=s3; d=d3; off=i-208896; }
  else if (i < 422912) { s=s4; d=d4; off=i-294912; }
  else if (i < 614912) { s=s5; d=d5; off=i-422912; }
  else return;
  float4 v = *(const float4*)(s + (size_t)off*4);
  ushort4 o = { f2bf(v.x), f2bf(v.y), f2bf(v.z), f2bf(v.w) };
  *(ushort4*)(d + (size_t)off*4) = o;
}

// ================= k_bags: mon bag + visit bags + weight/age (bf16 tables) =================
// grid (3072,3) block 256. y=0/1: mon p=y, 8 rows/block. y=2: x<1152 visit bags
// (2 rows/block of 2304), 1152<=x<1920 weight/age (2 rows/block of 1536).
__global__ __launch_bounds__(256) void k_bags(const int* __restrict__ vids, const int* __restrict__ mids,
    const u16* __restrict__ embv_b, const u16* __restrict__ embm_b,
    const float* __restrict__ wv, const float* __restrict__ av,
    const float* __restrict__ ww, const float* __restrict__ wb,
    const float* __restrict__ aw, const float* __restrict__ ab,
    u16* __restrict__ mon_xT, u16* __restrict__ vis_org, u16* __restrict__ hin2T){
  int y = blockIdx.y;
  if (y < 2){
    int p = y;
    int rid = threadIdx.x >> 5, lane32 = threadIdx.x & 31, d0 = lane32*4;
    __shared__ int ids[8][16];
    if (threadIdx.x < 128){
      int rr = threadIdx.x >> 4, c = threadIdx.x & 15;
      int f = 2*p + (c>>3), cm = c & 7;
      ids[rr][c] = mids[((size_t)f*24576 + (size_t)blockIdx.x*8 + rr)*8 + cm];
    }
    __syncthreads();
    const u16* e1 = embm_b + (size_t)(2*p)*1000*128;
    const u16* e2 = embm_b + (size_t)(2*p+1)*1000*128;
    float a0=0.f,a1=0.f,a2=0.f,a3=0.f;
    #pragma unroll
    for (int c = 0; c < 8; ++c){
      int i1 = ids[rid][c], i2 = ids[rid][8+c];
      if (i1 && i2){
        uint2 a = *(const uint2*)(e1 + (size_t)i1*128 + d0);
        uint2 b = *(const uint2*)(e2 + (size_t)i2*128 + d0);
        a0 += bflo(a.x)*bflo(b.x); a1 += bfhi(a.x)*bfhi(b.x);
        a2 += bflo(a.y)*bflo(b.y); a3 += bfhi(a.y)*bfhi(b.y);
      }
    }
    size_t nm = (size_t)blockIdx.x*8 + rid;
    int bv = (int)(nm >> 5), m = (int)(nm & 31);
    ushort4 o = { f2bf(a0), f2bf(a1), f2bf(a2), f2bf(a3) };
    *(ushort4*)(mon_xT + (size_t)p*24576*128 + ((size_t)m*768 + bv)*128 + d0) = o;
  } else {
    int x = blockIdx.x;
    int sub = threadIdx.x >> 7, d = threadIdx.x & 127;
    if (x < 1152){
      __shared__ int ids[2][48];
      int row = x*2 + sub;
      int k = row / 768, bv = row - k*768;
      if (d < 48) ids[sub][d] = vids[((size_t)k*768 + bv)*48 + d];
      __syncthreads();
      const u16* eb = embv_b + (size_t)k*2000*128;
      float acc = 0.f;
      #pragma unroll 4
      for (int c = 0; c < 48; ++c){ int id = ids[sub][c]; if (id) acc += bf2f(eb[(size_t)id*128 + d]); }
      vis_org[((size_t)k*768 + bv)*128 + d] = f2bf(acc);
    } else if (x < 1920){
      int grow = (x - 1152)*2 + sub;
      int sidx = grow >= 768 ? 1 : 0;
      int row = grow - sidx*768;
      const float* vals = sidx ? av : wv;
      const float* wgt  = sidx ? aw : ww;
      const float* bias = sidx ? ab : wb;
      float v = vals[row];
      float h = (v != 0.f) ? (v * wgt[d] + bias[d]) : 0.f;
      int b = row >> 4, vv = row & 15;
      hin2T[((size_t)(5+sidx)*768 + (size_t)vv*48 + b)*128 + d] = f2bf(h);
    }
  }
}

// ================= fused GRU (r6 schedule + GH-merge) =================
// phase 0: grid (48,7).
//   s<2 : T=32, A=mon_xT[s] (rstride=768*128), mgru[s], out hin2T[slot 0x32140].
//   s=2..4: T=32, A=vis_org[s-2] (rstride=0, const gi), mgru[s], out slot.
//   s=5,6 (x<3): T=16, A=hin2T[s] (rstride=48*128), vgru[s], out h2[s].
// phase 1: grid (3,5): visit streams s=0..4, vi=0x6514320 nibble, out h2[s].

#define BARRIER() asm volatile("s_waitcnt lgkmcnt(0)\n\ts_barrier" ::: "memory")

#define ALOAD(S, tt) { int t_=(tt); if (t_>=T) t_=0; \
  const u16* p_ = ap + (size_t)t_*rstride; \
  S[0]=*(const bf8*)(p_); S[1]=*(const bf8*)(p_+32); \
  S[2]=*(const bf8*)(p_+64); S[3]=*(const bf8*)(p_+96); }

// G0 = (bi_r+bh_r) + x@Wir ; G1 = (bi_z+bh_z) + x@Wiz ; G2 = bi_n + x@Win
#define GIMM(G0,G1,G2,S) { \
  f4 t0_={bs0_,bs0_,bs0_,bs0_}; G0=t0_; \
  f4 t1_={bs1_,bs1_,bs1_,bs1_}; G1=t1_; \
  f4 t2_={bin_,bin_,bin_,bin_}; G2=t2_; \
  G0=mfma16(S[0],wfi[0][0],G0); G0=mfma16(S[1],wfi[0][1],G0); \
  G0=mfma16(S[2],wfi[0][2],G0); G0=mfma16(S[3],wfi[0][3],G0); \
  G1=mfma16(S[0],wfi[1][0],G1); G1=mfma16(S[1],wfi[1][1],G1); \
  G1=mfma16(S[2],wfi[1][2],G1); G1=mfma16(S[3],wfi[1][3],G1); \
  G2=mfma16(S[0],wfi[2][0],G2); G2=mfma16(S[1],wfi[2][1],G2); \
  G2=mfma16(S[2],wfi[2][2],G2); G2=mfma16(S[3],wfi[2][3],G2); }

// h@Whh chained into G0,G1 (C-operand); AN = bh_n + h@Whn. Reads hlds[cur].
#define GH(G0,G1,AN) { \
  bf8 hf0_=*(const bf8*)&hlds[cur][lr][lq*8]; \
  bf8 hf1_=*(const bf8*)&hlds[cur][lr][32+lq*8]; \
  bf8 hf2_=*(const bf8*)&hlds[cur][lr][64+lq*8]; \
  bf8 hf3_=*(const bf8*)&hlds[cur][lr][96+lq*8]; \
  f4 an_={bhn_,bhn_,bhn_,bhn_}; AN=an_; \
  G0=mfma16(hf0_,wfh[0][0],G0); G0=mfma16(hf1_,wfh[0][1],G0); \
  G0=mfma16(hf2_,wfh[0][2],G0); G0=mfma16(hf3_,wfh[0][3],G0); \
  G1=mfma16(hf0_,wfh[1][0],G1); G1=mfma16(hf1_,wfh[1][1],G1); \
  G1=mfma16(hf2_,wfh[1][2],G1); G1=mfma16(hf3_,wfh[1][3],G1); \
  AN=mfma16(hf0_,wfh[2][0],AN); AN=mfma16(hf1_,wfh[2][1],AN); \
  AN=mfma16(hf2_,wfh[2][2],AN); AN=mfma16(hf3_,wfh[2][3],AN); }

// gates -> h_{t+1}; ds_write; raw barrier; flip cur. (G read-only here.)
#define GATES(G0,G1,G2,AN) { int nxt_=cur^1; \
  _Pragma("unroll") \
  for (int r=0;r<4;++r){ \
    float rr_=sigm(G0[r]); \
    float zz_=sigm(G1[r]); \
    float nn_=tanh_f(G2[r]+rr_*AN[r]); \
    float hv_=(1.0f-zz_)*nn_+zz_*hp[r]; hp[r]=hv_; \
    hlds[nxt_][lq*4+r][w*16+lr]=f2bf(hv_); } \
  BARRIER(); cur=nxt_; }

// r6 schedule: GH -> GATES(+barrier) -> GIMM rebuild -> ALOAD refill.
// Post-barrier GIMM MFMAs overlap the NEXT step's ds_read latency.
#define STEPB(G0,G1,G2,SN,tt) { \
  GH(G0,G1,ANr); \
  GATES(G0,G1,G2,ANr); \
  if ((tt)+2 < T){ GIMM(G0,G1,G2,SN); } \
  ALOAD(SN,(tt)+4); }

__global__ __launch_bounds__(512, 2) void k_gru(int phase,
    const u16* __restrict__ mon_xT, const u16* __restrict__ vis_org,
    u16* __restrict__ hin2T, u16* __restrict__ h2,
    const u16* __restrict__ mWih, const float* __restrict__ mbih,
    const u16* __restrict__ mWhh, const float* __restrict__ mbhh,
    const u16* __restrict__ vWih, const float* __restrict__ vbih,
    const u16* __restrict__ vWhh, const float* __restrict__ vbhh){
  int s = blockIdx.y, g = blockIdx.x;
  const u16* A; size_t rstride; int T, oMode; u16* ho;
  const u16 *Wi, *Wh; const float *biP, *bhP;
  if (phase == 0 && s < 5){
    T = 32; oMode = 0;
    if (s < 2){ A = mon_xT + (size_t)s*24576*128; rstride = 768*128; }
    else      { A = vis_org + (size_t)(s-2)*768*128; rstride = 0; }
    Wi = mWih + (size_t)s*49152; Wh = mWhh + (size_t)s*49152;
    biP = mbih + (size_t)s*384;  bhP = mbhh + (size_t)s*384;
    int slot = (0x32140u >> (4*s)) & 15;
    ho = hin2T + (size_t)slot*768*128;
  } else {
    if (g >= 3) return;
    T = 16; oMode = 1;
    A = hin2T + (size_t)s*768*128; rstride = 48*128;
    int vi = (0x6514320u >> (4*s)) & 15;
    Wi = vWih + (size_t)vi*49152; Wh = vWhh + (size_t)vi*49152;
    biP = vbih + (size_t)vi*384;  bhP = vbhh + (size_t)vi*384;
    ho = h2 + (size_t)s*48*128;
  }

  int w = threadIdx.x >> 6, l = threadIdx.x & 63;
  int lr = l & 15, lq = l >> 4;

  // wave w owns gate-col-chunk w*16..+16 of r,z,n (tiles w, 8+w, 16+w)
  bf8 wfi[3][4], wfh[3][4];
  #pragma unroll
  for (int j = 0; j < 3; ++j){
    int colb = (w + 8*j)*16;
    const u16* wpi = Wi + (size_t)(colb + lr)*128 + lq*8;
    const u16* wph = Wh + (size_t)(colb + lr)*128 + lq*8;
    #pragma unroll
    for (int kt = 0; kt < 4; ++kt){
      wfi[j][kt] = *(const bf8*)(wpi + kt*32);
      wfh[j][kt] = *(const bf8*)(wph + kt*32);
    }
  }
  float bs0_ = biP[w*16 + lr]      + bhP[w*16 + lr];        // r: bi+bh
  float bs1_ = biP[(8+w)*16 + lr]  + bhP[(8+w)*16 + lr];    // z: bi+bh
  float bin_ = biP[(16+w)*16 + lr];                          // n: bi only
  float bhn_ = bhP[(16+w)*16 + lr];                          // n: bh (in AN)

  const u16* ap = A + (size_t)(g*16 + lr)*128 + lq*8;
  __shared__ u16 hlds[2][16][132];   // 66-dword row stride: conflict-free b128
  float hp[4] = {0.f,0.f,0.f,0.f};
  int cur = 0;
  f4 ANr;

  if (rstride){
    bf8 S0[4], S1[4];
    f4 gE0,gE1,gE2, gO0,gO1,gO2;
    ALOAD(S0,0); ALOAD(S1,1);
    GIMM(gE0,gE1,gE2,S0); ALOAD(S0,2);      // gi(0); A(2) in flight
    GIMM(gO0,gO1,gO2,S1); ALOAD(S1,3);      // gi(1); A(3) in flight
    { // t=0: h0=0 -> gh contribution is just the (pre-summed) biases
      f4 an0={bhn_,bhn_,bhn_,bhn_}; ANr=an0;
      GATES(gE0,gE1,gE2,ANr);
    }
    GIMM(gE0,gE1,gE2,S0); ALOAD(S0,4);      // gi(2); A(4) in flight
    STEPB(gO0,gO1,gO2,S1,1);                // t=1: consume gi(1), build gi(3)
    for (int t = 2; t < T; t += 2){
      STEPB(gE0,gE1,gE2,S0,t);
      STEPB(gO0,gO1,gO2,S1,t+1);
    }
  } else {
    f4 C0,C1,C2;
    {
      bf8 S0[4];
      ALOAD(S0,0);
      GIMM(C0,C1,C2,S0);                    // constant gi (+bias), computed once
    }
    { // t=0
      f4 an0={bhn_,bhn_,bhn_,bhn_}; ANr=an0;
      GATES(C0,C1,C2,ANr);
    }
    for (int t = 1; t < T; ++t){
      f4 G0=C0, G1=C1;
      GH(G0,G1,ANr);
      GATES(G0,G1,C2,ANr);
    }
  }

  if (oMode == 0){
    #pragma unroll
    for (int r = 0; r < 4; ++r)
      ho[((size_t)(lq*4+r)*48 + g)*128 + w*16 + lr] = f2bf(hp[r]);
  } else {
    #pragma unroll
    for (int r = 0; r < 4; ++r)
      ho[((size_t)(g*16 + lq*4 + r))*128 + w*16 + lr] = f2bf(hp[r]);
  }
}

// ================= final projection =================
__global__ __launch_bounds__(256) void k_final(const u16* __restrict__ h2,
                                               const float* __restrict__ W,
                                               const float* __restrict__ Bias,
                                               float* __restrict__ out){
  int b = blockIdx.x, t = threadIdx.x;
  __shared__ float emb[896];
  for (int i = t; i < 896; i += 256){
    int j = i >> 7, d = i & 127;
    float v = bf2f(h2[((size_t)j*48 + b)*128 + d]);
    if (j >= 1 && j <= 3) v *= 2.0f;   // slots 1..3 appear twice in reference sum
    emb[i] = fmaxf(v, 0.f);
  }
  __syncthreads();
  float acc = Bias[t];
  const float* wp = W + (size_t)t*896;
  for (int i = 0; i < 896; i += 8){
    float4 w0 = *(const float4*)(wp + i);
    float4 w1 = *(const float4*)(wp + i + 4);
    acc += w0.x*emb[i]   + w0.y*emb[i+1] + w0.z*emb[i+2] + w0.w*emb[i+3];
    acc += w1.x*emb[i+4] + w1.y*emb[i+5] + w1.z*emb[i+6] + w1.w*emb[i+7];
  }
  out[(size_t)b*256 + t] = acc;
}

extern "C" void kernel_launch(void* const* d_in, const int* in_sizes, int n_in,
                              void* d_out, int out_size, void* d_ws, size_t ws_size,
                              hipStream_t stream){
  const int*   visit_ids   = (const int*)d_in[0];
  const int*   mon_ids     = (const int*)d_in[1];
  const float* weight_vals = (const float*)d_in[2];
  const float* age_vals    = (const float*)d_in[3];
  const float* emb_visit   = (const float*)d_in[4];
  const float* emb_mon     = (const float*)d_in[5];
  const float* mgru_Wih    = (const float*)d_in[6];
  const float* mgru_Whh    = (const float*)d_in[7];
  const float* mgru_bih    = (const float*)d_in[8];
  const float* mgru_bhh    = (const float*)d_in[9];
  const float* vgru_Wih    = (const float*)d_in[10];
  const float* vgru_Whh    = (const float*)d_in[11];
  const float* vgru_bih    = (const float*)d_in[12];
  const float* vgru_bhh    = (const float*)d_in[13];
  const float* fc_w_w      = (const float*)d_in[14];
  const float* fc_w_b      = (const float*)d_in[15];
  const float* fc_a_w      = (const float*)d_in[16];
  const float* fc_a_b      = (const float*)d_in[17];
  const float* fc_out_w    = (const float*)d_in[18];
  const float* fc_out_b    = (const float*)d_in[19];

  char* ws = (char*)d_ws;
  size_t o = 0;
  u16* mWih_b  = (u16*)(ws+o); o += 5ull*384*128*2;
  u16* mWhh_b  = (u16*)(ws+o); o += 5ull*384*128*2;
  u16* vWih_b  = (u16*)(ws+o); o += 7ull*384*128*2;
  u16* vWhh_b  = (u16*)(ws+o); o += 7ull*384*128*2;
  u16* embm_b  = (u16*)(ws+o); o += 4ull*1000*128*2;
  u16* embv_b  = (u16*)(ws+o); o += 3ull*2000*128*2;
  u16* mon_xT  = (u16*)(ws+o); o += 2ull*24576*128*2;    // [p][m*768+bv][128]
  u16* vis_org = (u16*)(ws+o); o += 3ull*768*128*2;
  u16* hin2T   = (u16*)(ws+o); o += 7ull*768*128*2;      // [slot][v*48+b][128]
  u16* h2      = (u16*)(ws+o); o += 7ull*48*128*2;       // ~18 MB total

  k_prep<<<2402, 256, 0, stream>>>(mgru_Wih, mgru_Whh, vgru_Wih, vgru_Whh, emb_mon, emb_visit,
                                   mWih_b, mWhh_b, vWih_b, vWhh_b, embm_b, embv_b);
  k_bags<<<dim3(3072,3), 256, 0, stream>>>(visit_ids, mon_ids, embv_b, embm_b,
      weight_vals, age_vals, fc_w_w, fc_w_b, fc_a_w, fc_a_b,
      mon_xT, vis_org, hin2T);
  // phase 0: monitor-level streams 0..4 (48 blocks each) + visit streams 5,6 (3 blocks)
  k_gru<<<dim3(48,7), 512, 0, stream>>>(0, mon_xT, vis_org, hin2T, h2,
      mWih_b, mgru_bih, mWhh_b, mgru_bhh, vWih_b, vgru_bih, vWhh_b, vgru_bhh);
  // phase 1: visit-level streams 0..4
  k_gru<<<dim3(3,5), 512, 0, stream>>>(1, mon_xT, vis_org, hin2T, h2,
      mWih_b, mgru_bih, mWhh_b, mgru_bhh, vWih_b, vgru_bih, vWhh_b, vgru_bhh);
  k_final<<<48, 256, 0, stream>>>(h2, fc_out_w, fc_out_b, (float*)d_out);
}

// Round 11
// 125.059 us; speedup vs baseline: 1.5542x; 1.1225x over previous
//
#include <hip/hip_runtime.h>
#include <stdint.h>

// PersonalMed on MI355X. B=48,V=16,M=32,C=48,CM=8,D=128,OUT=256. f32 in/out.
// Round-11: (1) unfold streams 5,6 back to phase-1 -- phase-0 restored to the
// exact r6 grid (48,5) that measured 45us (r9/r10's fold correlated with a +9us
// regression; controlled revert). GH-merge kept. (2) front-end in ONE dispatch:
// k_bags reads f32 tables directly and converts GRU weights in its spare
// x-blocks. 4 dispatches total.
// Ledger: IEEE-div gates were the 60us floor (r6, -15); vmcnt-drain barrier
// neutral (r5); 2 chains/wave ~doubles step (r7/r8); pre-barrier work paid xT (r9).

typedef unsigned short u16;
typedef uint32_t u32;
typedef short bf8 __attribute__((ext_vector_type(8)));   // 8 bf16 = 4 VGPRs
typedef float f4 __attribute__((ext_vector_type(4)));

static __device__ __forceinline__ float bf2f(u16 b){ u32 u=((u32)b)<<16; float f; __builtin_memcpy(&f,&u,4); return f; }
static __device__ __forceinline__ u16 f2bf(float f){ u32 u; __builtin_memcpy(&u,&f,4); u32 r=(u+0x7fffu+((u>>16)&1u))>>16; return (u16)r; }
static __device__ __forceinline__ f4 mfma16(bf8 a, bf8 b, f4 c){ return __builtin_amdgcn_mfma_f32_16x16x32_bf16(a,b,c,0,0,0); }

#if __has_builtin(__builtin_amdgcn_exp2f)
static __device__ __forceinline__ float fexp2(float x){ return __builtin_amdgcn_exp2f(x); }
#else
static __device__ __forceinline__ float fexp2(float x){ float r; asm volatile("v_exp_f32 %0, %1" : "=v"(r) : "v"(x)); return r; }
#endif
#if __has_builtin(__builtin_amdgcn_rcpf)
static __device__ __forceinline__ float frcp(float x){ return __builtin_amdgcn_rcpf(x); }
#else
static __device__ __forceinline__ float frcp(float x){ float r; asm volatile("v_rcp_f32 %0, %1" : "=v"(r) : "v"(x)); return r; }
#endif
#define LOG2E 1.44269504089f
static __device__ __forceinline__ float sigm(float x){ return frcp(1.0f + fexp2(-LOG2E*x)); }
static __device__ __forceinline__ float tanh_f(float x){ return 1.0f - 2.0f*frcp(1.0f + fexp2((2.0f*LOG2E)*x)); }

// ============ k_bags: ALL front-end work in one dispatch, grid (3072,3) block 256 ============
// y=0/1 : monitor bag p=y from f32 tables, 8 rows/block.
// y=2   : x<1152: visit bags from f32 (2 rows/block of 2304)
//         1152<=x<1920: weight/age linears (2 rows/block of 1536)
//         1920<=x<3072: GRU weights f32->bf16 (294912 float4s over 1152 blocks)
__global__ __launch_bounds__(256) void k_bags(const int* __restrict__ vids, const int* __restrict__ mids,
    const float* __restrict__ embv, const float* __restrict__ embm,
    const float* __restrict__ wv, const float* __restrict__ av,
    const float* __restrict__ ww, const float* __restrict__ wb,
    const float* __restrict__ aw, const float* __restrict__ ab,
    const float* __restrict__ mWih_f, const float* __restrict__ mWhh_f,
    const float* __restrict__ vWih_f, const float* __restrict__ vWhh_f,
    u16* __restrict__ mWih_b, u16* __restrict__ mWhh_b,
    u16* __restrict__ vWih_b, u16* __restrict__ vWhh_b,
    u16* __restrict__ mon_xT, u16* __restrict__ vis_org, u16* __restrict__ hin2T){
  int y = blockIdx.y;
  if (y < 2){
    int p = y;
    int rid = threadIdx.x >> 5, lane32 = threadIdx.x & 31, d0 = lane32*4;
    __shared__ int ids[8][16];
    if (threadIdx.x < 128){
      int rr = threadIdx.x >> 4, c = threadIdx.x & 15;
      int f = 2*p + (c>>3), cm = c & 7;
      ids[rr][c] = mids[((size_t)f*24576 + (size_t)blockIdx.x*8 + rr)*8 + cm];
    }
    __syncthreads();
    const float* e1 = embm + (size_t)(2*p)*1000*128;
    const float* e2 = embm + (size_t)(2*p+1)*1000*128;
    float a0=0.f,a1=0.f,a2=0.f,a3=0.f;
    #pragma unroll
    for (int c = 0; c < 8; ++c){
      int i1 = ids[rid][c], i2 = ids[rid][8+c];
      if (i1 && i2){
        float4 a = *(const float4*)(e1 + (size_t)i1*128 + d0);
        float4 b = *(const float4*)(e2 + (size_t)i2*128 + d0);
        a0 += a.x*b.x; a1 += a.y*b.y; a2 += a.z*b.z; a3 += a.w*b.w;
      }
    }
    size_t nm = (size_t)blockIdx.x*8 + rid;
    int bv = (int)(nm >> 5), m = (int)(nm & 31);
    ushort4 o = { f2bf(a0), f2bf(a1), f2bf(a2), f2bf(a3) };
    *(ushort4*)(mon_xT + (size_t)p*24576*128 + ((size_t)m*768 + bv)*128 + d0) = o;
  } else {
    int x = blockIdx.x;
    if (x < 1152){                                  // visit bags
      __shared__ int ids[2][48];
      int sub = threadIdx.x >> 7, d = threadIdx.x & 127;
      int row = x*2 + sub;
      int k = row / 768, bv = row - k*768;
      if (d < 48) ids[sub][d] = vids[((size_t)k*768 + bv)*48 + d];
      __syncthreads();
      const float* eb = embv + (size_t)k*2000*128;
      float acc = 0.f;
      #pragma unroll 4
      for (int c = 0; c < 48; ++c){ int id = ids[sub][c]; if (id) acc += eb[(size_t)id*128 + d]; }
      vis_org[((size_t)k*768 + bv)*128 + d] = f2bf(acc);
    } else if (x < 1920){                           // weight/age linears
      int sub = threadIdx.x >> 7, d = threadIdx.x & 127;
      int grow = (x - 1152)*2 + sub;
      int sidx = grow >= 768 ? 1 : 0;
      int row = grow - sidx*768;
      const float* vals = sidx ? av : wv;
      const float* wgt  = sidx ? aw : ww;
      const float* bias = sidx ? ab : wb;
      float v = vals[row];
      float h = (v != 0.f) ? (v * wgt[d] + bias[d]) : 0.f;
      int b = row >> 4, vv = row & 15;
      hin2T[((size_t)(5+sidx)*768 + (size_t)vv*48 + b)*128 + d] = f2bf(h);
    } else {                                        // GRU weight conversion
      int i = (x - 1920)*256 + threadIdx.x;         // float4 index < 294912
      const float* s; u16* d; int off;
      if      (i < 61440)  { s=mWih_f; d=mWih_b; off=i; }
      else if (i < 122880) { s=mWhh_f; d=mWhh_b; off=i-61440; }
      else if (i < 208896) { s=vWih_f; d=vWih_b; off=i-122880; }
      else                 { s=vWhh_f; d=vWhh_b; off=i-208896; }
      float4 v = *(const float4*)(s + (size_t)off*4);
      ushort4 o = { f2bf(v.x), f2bf(v.y), f2bf(v.z), f2bf(v.w) };
      *(ushort4*)(d + (size_t)off*4) = o;
    }
  }
}

// ================= fused GRU (r6 schedule + GH-merge) =================
// phase 0: grid (48,5). s<2: T=32, A=mon_xT[s] (rstride=768*128); s=2..4:
//   T=32, A=vis_org[s-2] (rstride=0, const gi). mgru[s], out hin2T[slot 0x32140].
// phase 1: grid (3,7). T=16, A=hin2T[s] (rstride=48*128), vgru[0x6514320 nibble],
//   out h2[s].

#define BARRIER() asm volatile("s_waitcnt lgkmcnt(0)\n\ts_barrier" ::: "memory")

#define ALOAD(S, tt) { int t_=(tt); if (t_>=T) t_=0; \
  const u16* p_ = ap + (size_t)t_*rstride; \
  S[0]=*(const bf8*)(p_); S[1]=*(const bf8*)(p_+32); \
  S[2]=*(const bf8*)(p_+64); S[3]=*(const bf8*)(p_+96); }

// G0 = (bi_r+bh_r) + x@Wir ; G1 = (bi_z+bh_z) + x@Wiz ; G2 = bi_n + x@Win
#define GIMM(G0,G1,G2,S) { \
  f4 t0_={bs0_,bs0_,bs0_,bs0_}; G0=t0_; \
  f4 t1_={bs1_,bs1_,bs1_,bs1_}; G1=t1_; \
  f4 t2_={bin_,bin_,bin_,bin_}; G2=t2_; \
  G0=mfma16(S[0],wfi[0][0],G0); G0=mfma16(S[1],wfi[0][1],G0); \
  G0=mfma16(S[2],wfi[0][2],G0); G0=mfma16(S[3],wfi[0][3],G0); \
  G1=mfma16(S[0],wfi[1][0],G1); G1=mfma16(S[1],wfi[1][1],G1); \
  G1=mfma16(S[2],wfi[1][2],G1); G1=mfma16(S[3],wfi[1][3],G1); \
  G2=mfma16(S[0],wfi[2][0],G2); G2=mfma16(S[1],wfi[2][1],G2); \
  G2=mfma16(S[2],wfi[2][2],G2); G2=mfma16(S[3],wfi[2][3],G2); }

// h@Whh chained into G0,G1 (C-operand); AN = bh_n + h@Whn. Reads hlds[cur].
#define GH(G0,G1,AN) { \
  bf8 hf0_=*(const bf8*)&hlds[cur][lr][lq*8]; \
  bf8 hf1_=*(const bf8*)&hlds[cur][lr][32+lq*8]; \
  bf8 hf2_=*(const bf8*)&hlds[cur][lr][64+lq*8]; \
  bf8 hf3_=*(const bf8*)&hlds[cur][lr][96+lq*8]; \
  f4 an_={bhn_,bhn_,bhn_,bhn_}; AN=an_; \
  G0=mfma16(hf0_,wfh[0][0],G0); G0=mfma16(hf1_,wfh[0][1],G0); \
  G0=mfma16(hf2_,wfh[0][2],G0); G0=mfma16(hf3_,wfh[0][3],G0); \
  G1=mfma16(hf0_,wfh[1][0],G1); G1=mfma16(hf1_,wfh[1][1],G1); \
  G1=mfma16(hf2_,wfh[1][2],G1); G1=mfma16(hf3_,wfh[1][3],G1); \
  AN=mfma16(hf0_,wfh[2][0],AN); AN=mfma16(hf1_,wfh[2][1],AN); \
  AN=mfma16(hf2_,wfh[2][2],AN); AN=mfma16(hf3_,wfh[2][3],AN); }

// gates -> h_{t+1}; ds_write; raw barrier; flip cur.
#define GATES(G0,G1,G2,AN) { int nxt_=cur^1; \
  _Pragma("unroll") \
  for (int r=0;r<4;++r){ \
    float rr_=sigm(G0[r]); \
    float zz_=sigm(G1[r]); \
    float nn_=tanh_f(G2[r]+rr_*AN[r]); \
    float hv_=(1.0f-zz_)*nn_+zz_*hp[r]; hp[r]=hv_; \
    hlds[nxt_][lq*4+r][w*16+lr]=f2bf(hv_); } \
  BARRIER(); cur=nxt_; }

// r6 schedule: GH -> GATES(+barrier) -> GIMM rebuild -> ALOAD refill.
#define STEPB(G0,G1,G2,SN,tt) { \
  GH(G0,G1,ANr); \
  GATES(G0,G1,G2,ANr); \
  if ((tt)+2 < T){ GIMM(G0,G1,G2,SN); } \
  ALOAD(SN,(tt)+4); }

__global__ __launch_bounds__(512, 2) void k_gru(int phase,
    const u16* __restrict__ mon_xT, const u16* __restrict__ vis_org,
    u16* __restrict__ hin2T, u16* __restrict__ h2,
    const u16* __restrict__ mWih, const float* __restrict__ mbih,
    const u16* __restrict__ mWhh, const float* __restrict__ mbhh,
    const u16* __restrict__ vWih, const float* __restrict__ vbih,
    const u16* __restrict__ vWhh, const float* __restrict__ vbhh){
  int s = blockIdx.y, g = blockIdx.x;
  const u16* A; size_t rstride; int T, oMode; u16* ho;
  const u16 *Wi, *Wh; const float *biP, *bhP;
  if (phase == 0){
    T = 32; oMode = 0;
    if (s < 2){ A = mon_xT + (size_t)s*24576*128; rstride = 768*128; }
    else      { A = vis_org + (size_t)(s-2)*768*128; rstride = 0; }
    Wi = mWih + (size_t)s*49152; Wh = mWhh + (size_t)s*49152;
    biP = mbih + (size_t)s*384;  bhP = mbhh + (size_t)s*384;
    int slot = (0x32140u >> (4*s)) & 15;
    ho = hin2T + (size_t)slot*768*128;
  } else {
    T = 16; oMode = 1;
    A = hin2T + (size_t)s*768*128; rstride = 48*128;
    int vi = (0x6514320u >> (4*s)) & 15;
    Wi = vWih + (size_t)vi*49152; Wh = vWhh + (size_t)vi*49152;
    biP = vbih + (size_t)vi*384;  bhP = vbhh + (size_t)vi*384;
    ho = h2 + (size_t)s*48*128;
  }

  int w = threadIdx.x >> 6, l = threadIdx.x & 63;
  int lr = l & 15, lq = l >> 4;

  // wave w owns gate-col-chunk w*16..+16 of r,z,n (tiles w, 8+w, 16+w)
  bf8 wfi[3][4], wfh[3][4];
  #pragma unroll
  for (int j = 0; j < 3; ++j){
    int colb = (w + 8*j)*16;
    const u16* wpi = Wi + (size_t)(colb + lr)*128 + lq*8;
    const u16* wph = Wh + (size_t)(colb + lr)*128 + lq*8;
    #pragma unroll
    for (int kt = 0; kt < 4; ++kt){
      wfi[j][kt] = *(const bf8*)(wpi + kt*32);
      wfh[j][kt] = *(const bf8*)(wph + kt*32);
    }
  }
  float bs0_ = biP[w*16 + lr]      + bhP[w*16 + lr];        // r: bi+bh
  float bs1_ = biP[(8+w)*16 + lr]  + bhP[(8+w)*16 + lr];    // z: bi+bh
  float bin_ = biP[(16+w)*16 + lr];                          // n: bi only
  float bhn_ = bhP[(16+w)*16 + lr];                          // n: bh (in AN)

  const u16* ap = A + (size_t)(g*16 + lr)*128 + lq*8;
  __shared__ u16 hlds[2][16][132];   // 66-dword row stride: conflict-free b128
  float hp[4] = {0.f,0.f,0.f,0.f};
  int cur = 0;
  f4 ANr;

  if (rstride){
    bf8 S0[4], S1[4];
    f4 gE0,gE1,gE2, gO0,gO1,gO2;
    ALOAD(S0,0); ALOAD(S1,1);
    GIMM(gE0,gE1,gE2,S0); ALOAD(S0,2);      // gi(0); A(2) in flight
    GIMM(gO0,gO1,gO2,S1); ALOAD(S1,3);      // gi(1); A(3) in flight
    { // t=0: h0=0 -> gh contribution is just the (pre-summed) biases
      f4 an0={bhn_,bhn_,bhn_,bhn_}; ANr=an0;
      GATES(gE0,gE1,gE2,ANr);
    }
    GIMM(gE0,gE1,gE2,S0); ALOAD(S0,4);      // gi(2); A(4) in flight
    STEPB(gO0,gO1,gO2,S1,1);                // t=1: consume gi(1), build gi(3)
    for (int t = 2; t < T; t += 2){
      STEPB(gE0,gE1,gE2,S0,t);
      STEPB(gO0,gO1,gO2,S1,t+1);
    }
  } else {
    f4 C0,C1,C2;
    {
      bf8 S0[4];
      ALOAD(S0,0);
      GIMM(C0,C1,C2,S0);                    // constant gi (+bias), computed once
    }
    { // t=0
      f4 an0={bhn_,bhn_,bhn_,bhn_}; ANr=an0;
      GATES(C0,C1,C2,ANr);
    }
    for (int t = 1; t < T; ++t){
      f4 G0=C0, G1=C1;
      GH(G0,G1,ANr);
      GATES(G0,G1,C2,ANr);
    }
  }

  if (oMode == 0){
    #pragma unroll
    for (int r = 0; r < 4; ++r)
      ho[((size_t)(lq*4+r)*48 + g)*128 + w*16 + lr] = f2bf(hp[r]);
  } else {
    #pragma unroll
    for (int r = 0; r < 4; ++r)
      ho[((size_t)(g*16 + lq*4 + r))*128 + w*16 + lr] = f2bf(hp[r]);
  }
}

// ================= final projection =================
__global__ __launch_bounds__(256) void k_final(const u16* __restrict__ h2,
                                               const float* __restrict__ W,
                                               const float* __restrict__ Bias,
                                               float* __restrict__ out){
  int b = blockIdx.x, t = threadIdx.x;
  __shared__ float emb[896];
  for (int i = t; i < 896; i += 256){
    int j = i >> 7, d = i & 127;
    float v = bf2f(h2[((size_t)j*48 + b)*128 + d]);
    if (j >= 1 && j <= 3) v *= 2.0f;   // slots 1..3 appear twice in reference sum
    emb[i] = fmaxf(v, 0.f);
  }
  __syncthreads();
  float acc = Bias[t];
  const float* wp = W + (size_t)t*896;
  for (int i = 0; i < 896; i += 8){
    float4 w0 = *(const float4*)(wp + i);
    float4 w1 = *(const float4*)(wp + i + 4);
    acc += w0.x*emb[i]   + w0.y*emb[i+1] + w0.z*emb[i+2] + w0.w*emb[i+3];
    acc += w1.x*emb[i+4] + w1.y*emb[i+5] + w1.z*emb[i+6] + w1.w*emb[i+7];
  }
  out[(size_t)b*256 + t] = acc;
}

extern "C" void kernel_launch(void* const* d_in, const int* in_sizes, int n_in,
                              void* d_out, int out_size, void* d_ws, size_t ws_size,
                              hipStream_t stream){
  const int*   visit_ids   = (const int*)d_in[0];
  const int*   mon_ids     = (const int*)d_in[1];
  const float* weight_vals = (const float*)d_in[2];
  const float* age_vals    = (const float*)d_in[3];
  const float* emb_visit   = (const float*)d_in[4];
  const float* emb_mon     = (const float*)d_in[5];
  const float* mgru_Wih    = (const float*)d_in[6];
  const float* mgru_Whh    = (const float*)d_in[7];
  const float* mgru_bih    = (const float*)d_in[8];
  const float* mgru_bhh    = (const float*)d_in[9];
  const float* vgru_Wih    = (const float*)d_in[10];
  const float* vgru_Whh    = (const float*)d_in[11];
  const float* vgru_bih    = (const float*)d_in[12];
  const float* vgru_bhh    = (const float*)d_in[13];
  const float* fc_w_w      = (const float*)d_in[14];
  const float* fc_w_b      = (const float*)d_in[15];
  const float* fc_a_w      = (const float*)d_in[16];
  const float* fc_a_b      = (const float*)d_in[17];
  const float* fc_out_w    = (const float*)d_in[18];
  const float* fc_out_b    = (const float*)d_in[19];

  char* ws = (char*)d_ws;
  size_t o = 0;
  u16* mWih_b  = (u16*)(ws+o); o += 5ull*384*128*2;
  u16* mWhh_b  = (u16*)(ws+o); o += 5ull*384*128*2;
  u16* vWih_b  = (u16*)(ws+o); o += 7ull*384*128*2;
  u16* vWhh_b  = (u16*)(ws+o); o += 7ull*384*128*2;
  u16* mon_xT  = (u16*)(ws+o); o += 2ull*24576*128*2;    // [p][m*768+bv][128]
  u16* vis_org = (u16*)(ws+o); o += 3ull*768*128*2;
  u16* hin2T   = (u16*)(ws+o); o += 7ull*768*128*2;      // [slot][v*48+b][128]
  u16* h2      = (u16*)(ws+o); o += 7ull*48*128*2;       // ~16.6 MB total

  // one front-end dispatch: bags + linears + weight conversion
  k_bags<<<dim3(3072,3), 256, 0, stream>>>(visit_ids, mon_ids, emb_visit, emb_mon,
      weight_vals, age_vals, fc_w_w, fc_w_b, fc_a_w, fc_a_b,
      mgru_Wih, mgru_Whh, vgru_Wih, vgru_Whh,
      mWih_b, mWhh_b, vWih_b, vWhh_b,
      mon_xT, vis_org, hin2T);
  // phase 0: monitor-level streams 0..4 (r6 shape)
  k_gru<<<dim3(48,5), 512, 0, stream>>>(0, mon_xT, vis_org, hin2T, h2,
      mWih_b, mgru_bih, mWhh_b, mgru_bhh, vWih_b, vgru_bih, vWhh_b, vgru_bhh);
  // phase 1: visit-level streams 0..6 (r6 shape)
  k_gru<<<dim3(3,7), 512, 0, stream>>>(1, mon_xT, vis_org, hin2T, h2,
      mWih_b, mgru_bih, mWhh_b, mgru_bhh, vWih_b, vgru_bih, vWhh_b, vgru_bhh);
  k_final<<<48, 256, 0, stream>>>(h2, fc_out_w, fc_out_b, (float*)d_out);
}